// Round 4
// baseline (1636.748 us; speedup 1.0000x reference)
//
#include <hip/hip_runtime.h>
#include <cstdint>
#include <cstddef>

#define WH 4096
#define CD 256
typedef long long i64;

typedef __attribute__((ext_vector_type(8))) _Float16 f16x8;
typedef __attribute__((ext_vector_type(4))) float f32x4;

#define AS1 __attribute__((address_space(1)))
#define AS3 __attribute__((address_space(3)))

__device__ __forceinline__ unsigned short f2h(float f) {
    _Float16 h = (_Float16)f;
    return __builtin_bit_cast(unsigned short, h);
}
__device__ __forceinline__ float h2f(unsigned short u) {
    return (float)__builtin_bit_cast(_Float16, u);
}
__device__ __forceinline__ void ld16_lds(const void* g, void* l) {
    __builtin_amdgcn_global_load_lds((AS1 void*)g, (AS3 void*)l, 16, 0, 0);
}

// -------- transpose f32 (src-stride CC) -> f16 split (dst-stride RR)
__global__ __launch_bounds__(256) void k_trans(const float* __restrict__ src,
                                               unsigned short* __restrict__ dhi,
                                               unsigned short* __restrict__ dlo,
                                               int RR, int CC, i64 ss, i64 ds) {
    __shared__ float t[32][33];
    const float* s = src + (i64)blockIdx.z * ss;
    const int c0 = blockIdx.x * 32, r0 = blockIdx.y * 32;
    const int tx = threadIdx.x, ty = threadIdx.y;
#pragma unroll
    for (int i = 0; i < 4; ++i)
        t[ty + i * 8][tx] = s[(i64)(r0 + ty + i * 8) * CC + c0 + tx];
    __syncthreads();
#pragma unroll
    for (int i = 0; i < 4; ++i) {
        const i64 idx = (i64)blockIdx.z * ds + (i64)(c0 + ty + i * 8) * RR + r0 + tx;
        const float v = t[tx][ty + i * 8];
        const unsigned short hi = f2h(v);
        dhi[idx] = hi;
        dlo[idx] = f2h(v - h2f(hi));
    }
}

// -------- NT GEMM, split-f16: C = (Ah+Al)(Bh+Bl)^T via 3 MFMA products.
// MODE 0: plain f32 store (logits -> Lb)
// MODE 1: bias+relu, store transposed f16-split (ax -> axt hi/lo)
// MODE 2: bias+relu, add split residual, f32 store (r -> outf)
// MODE 3: split-K (z = k-chunk, K = chunk len), atomicAdd f32 (attention -> outf)
template <int MODE>
__global__ __launch_bounds__(256) void k_gemm(
    const unsigned short* __restrict__ A, const unsigned short* __restrict__ A2, int lda, i64 sA,
    const unsigned short* __restrict__ B, const unsigned short* __restrict__ B2, int ldb, i64 sB,
    float* __restrict__ Cf, unsigned short* __restrict__ Chi, unsigned short* __restrict__ Clo,
    int ldc, i64 sC, int K,
    const float* __restrict__ bias,
    const unsigned short* __restrict__ addh, const unsigned short* __restrict__ addl) {
    __shared__ __align__(16) short lA[8192];
    __shared__ __align__(16) short lB[8192];
    const int z = blockIdx.z;
    i64 koff = 0;
    if constexpr (MODE == 3) {
        koff = (i64)z * K;
    } else {
        A += (i64)z * sA; A2 += (i64)z * sA;
        B += (i64)z * sB; B2 += (i64)z * sB;
    }

    const int tid = threadIdx.x;
    const int w = tid >> 6, l = tid & 63;
    const int wm = w >> 1, wn = w & 1;
    const int bm = blockIdx.y * 128, bn = blockIdx.x * 128;
    const int l15 = l & 15, lq = l >> 4;

    f32x4 acc[4][4] = {};

    for (int kt = 0; kt < K; kt += 32) {
        __syncthreads();
#pragma unroll
        for (int rr = 0; rr < 2; ++rr) {
            const int r = w + rr * 4;          // region 0..7
            const int kb = r >> 1, mh = r & 1;
            const int row = mh * 64 + l;
            const i64 ao = (i64)(bm + row) * lda + koff + kt + kb * 8;
            const i64 bo = (i64)(bn + row) * ldb + koff + kt + kb * 8;
            ld16_lds(A + ao, (char*)lA + r * 1024);
            ld16_lds(B + bo, (char*)lB + r * 1024);
            ld16_lds(A2 + ao, (char*)lA + 8192 + r * 1024);
            ld16_lds(B2 + bo, (char*)lB + 8192 + r * 1024);
        }
        __syncthreads();
        f16x8 ah[4], bh[4], al[4], bl[4];
#pragma unroll
        for (int i = 0; i < 4; ++i) {
            const int ia = (lq * 128 + wm * 64 + i * 16 + l15) * 8;
            const int ib = (lq * 128 + wn * 64 + i * 16 + l15) * 8;
            ah[i] = *(const f16x8*)(lA + ia);
            bh[i] = *(const f16x8*)(lB + ib);
            al[i] = *(const f16x8*)(lA + 4096 + ia);
            bl[i] = *(const f16x8*)(lB + 4096 + ib);
        }
#pragma unroll
        for (int i = 0; i < 4; ++i)
#pragma unroll
            for (int j = 0; j < 4; ++j) {
                acc[i][j] = __builtin_amdgcn_mfma_f32_16x16x32_f16(ah[i], bh[j], acc[i][j], 0, 0, 0);
                acc[i][j] = __builtin_amdgcn_mfma_f32_16x16x32_f16(ah[i], bl[j], acc[i][j], 0, 0, 0);
                acc[i][j] = __builtin_amdgcn_mfma_f32_16x16x32_f16(al[i], bh[j], acc[i][j], 0, 0, 0);
            }
    }

#pragma unroll
    for (int i = 0; i < 4; ++i)
#pragma unroll
        for (int j = 0; j < 4; ++j) {
            const int n = bn + wn * 64 + j * 16 + l15;
            const int m0 = bm + wm * 64 + i * 16 + lq * 4;
            float bv = 0.f;
            if constexpr (MODE == 1 || MODE == 2) bv = bias[n];
            if constexpr (MODE == 1) {
                unsigned short hv[4], lv[4];
#pragma unroll
                for (int r = 0; r < 4; ++r) {
                    const float v = fmaxf(acc[i][j][r] + bv, 0.f);
                    hv[r] = f2h(v);
                    lv[r] = f2h(v - h2f(hv[r]));
                }
                const i64 tb = (i64)z * sC + (i64)n * ldc + m0;
                *(ushort4*)(Chi + tb) = make_ushort4(hv[0], hv[1], hv[2], hv[3]);
                *(ushort4*)(Clo + tb) = make_ushort4(lv[0], lv[1], lv[2], lv[3]);
            } else {
#pragma unroll
                for (int r = 0; r < 4; ++r) {
                    float v = acc[i][j][r];
                    const i64 m = m0 + r;
                    const i64 idx = (i64)z * sC + m * ldc + n;
                    if constexpr (MODE == 0) {
                        Cf[idx] = v;
                    } else if constexpr (MODE == 2) {
                        v = fmaxf(v + bv, 0.f);
                        v += h2f(addh[idx]) + h2f(addl[idx]);
                        Cf[idx] = v;
                    } else {  // MODE 3
                        atomicAdd(&Cf[m * ldc + n], v);
                    }
                }
            }
        }
}

// -------- row stats: o_i = rowmax + ln(rowsum exp)
__global__ __launch_bounds__(256) void k_rowstat(const float* __restrict__ Lp,
                                                 float* __restrict__ o) {
    const i64 row = blockIdx.x;
    const float4* rp = (const float4*)(Lp + row * WH);
    const int t = threadIdx.x;
    float4 v[4];
#pragma unroll
    for (int k = 0; k < 4; ++k) v[k] = rp[t + 256 * k];
    float m = -3.4e38f;
#pragma unroll
    for (int k = 0; k < 4; ++k)
        m = fmaxf(m, fmaxf(fmaxf(v[k].x, v[k].y), fmaxf(v[k].z, v[k].w)));
#pragma unroll
    for (int off = 32; off >= 1; off >>= 1) m = fmaxf(m, __shfl_xor(m, off));
    __shared__ float red[4];
    if ((t & 63) == 0) red[t >> 6] = m;
    __syncthreads();
    m = fmaxf(fmaxf(red[0], red[1]), fmaxf(red[2], red[3]));
    float ssum = 0.f;
#pragma unroll
    for (int k = 0; k < 4; ++k)
        ssum += __expf(v[k].x - m) + __expf(v[k].y - m) + __expf(v[k].z - m) + __expf(v[k].w - m);
#pragma unroll
    for (int off = 32; off >= 1; off >>= 1) ssum += __shfl_xor(ssum, off);
    __syncthreads();
    if ((t & 63) == 0) red[t >> 6] = ssum;
    __syncthreads();
    if (t == 0) o[row] = m + __logf(red[0] + red[1] + red[2] + red[3]);
}

// -------- column partials: per (64-row block, col) online (max, expsum) of L - o_i
__global__ __launch_bounds__(256) void k_colpart(const float* __restrict__ L,
                                                 const float* __restrict__ o,
                                                 float2* __restrict__ part) {
    const int j = blockIdx.x * 256 + threadIdx.x;
    const int r0 = blockIdx.y * 64;
    float pm = -3.4e38f, ps = 0.f;
    for (int r = 0; r < 64; ++r) {
        const float x = L[(i64)(r0 + r) * WH + j] - o[r0 + r];
        if (x > pm) { ps *= __expf(pm - x); pm = x; }
        ps += __expf(x - pm);
    }
    part[(i64)blockIdx.y * WH + j] = make_float2(pm, ps);
}

// -------- column reduce -> (M_j, scale_j) with eps-clip semantics
__global__ __launch_bounds__(256) void k_colreduce(const float2* __restrict__ part,
                                                   float* __restrict__ colM,
                                                   float* __restrict__ colS) {
    const int j = blockIdx.x * 256 + threadIdx.x;
    float M = -3.4e38f, C = 0.f;
    for (int rb = 0; rb < 64; ++rb) {
        const float2 p = part[(i64)rb * WH + j];
        if (p.x > M) { C *= __expf(M - p.x); M = p.x; }
        C += p.y * __expf(p.x - M);
    }
    const float lnS = M + __logf(C);
    colM[j] = M;
    // s_j = e^M * C; if s >= 1e-12: A = e^(x-M)/C; else A = e^(x-M) * e^(M + ln 1e12)
    colS[j] = (lnS >= -27.6310211159f) ? (1.f / C) : __expf(M + 27.6310211159f);
}

// -------- write A = exp(L - o_i - M_j) * scale_j as f16 split (hi, lo), row-major
__global__ __launch_bounds__(256) void k_writeA(const float* __restrict__ L,
                                                const float* __restrict__ o,
                                                const float* __restrict__ colM,
                                                const float* __restrict__ colS,
                                                unsigned short* __restrict__ Ahi,
                                                unsigned short* __restrict__ Alo) {
    const i64 base = ((i64)blockIdx.x * 256 + threadIdx.x) * 8;
    const int i = (int)(base >> 12), j = (int)(base & 4095);
    const float oi = o[i];
    float x[8], cm[8], cs[8];
    *(float4*)(x)      = *(const float4*)(L + base);
    *(float4*)(x + 4)  = *(const float4*)(L + base + 4);
    *(float4*)(cm)     = *(const float4*)(colM + j);
    *(float4*)(cm + 4) = *(const float4*)(colM + j + 4);
    *(float4*)(cs)     = *(const float4*)(colS + j);
    *(float4*)(cs + 4) = *(const float4*)(colS + j + 4);
    unsigned short hv[8], lv[8];
#pragma unroll
    for (int k = 0; k < 8; ++k) {
        const float v = __expf(x[k] - oi - cm[k]) * cs[k];
        hv[k] = f2h(v);
        lv[k] = f2h(v - h2f(hv[k]));
    }
    *(ushort4*)(Ahi + base)     = make_ushort4(hv[0], hv[1], hv[2], hv[3]);
    *(ushort4*)(Ahi + base + 4) = make_ushort4(hv[4], hv[5], hv[6], hv[7]);
    *(ushort4*)(Alo + base)     = make_ushort4(lv[0], lv[1], lv[2], lv[3]);
    *(ushort4*)(Alo + base + 4) = make_ushort4(lv[4], lv[5], lv[6], lv[7]);
}

// -------- f32 -> (f16 hi, f16 lo) split
__global__ __launch_bounds__(256) void k_mksplit(const float* __restrict__ in,
                                                 unsigned short* __restrict__ hi,
                                                 unsigned short* __restrict__ lo, i64 n) {
    const i64 i = ((i64)blockIdx.x * 256 + threadIdx.x) * 4;
    if (i >= n) return;
    const float4 v = *(const float4*)(in + i);
    ushort4 h, l2;
    h.x = f2h(v.x); l2.x = f2h(v.x - h2f(h.x));
    h.y = f2h(v.y); l2.y = f2h(v.y - h2f(h.y));
    h.z = f2h(v.z); l2.z = f2h(v.z - h2f(h.z));
    h.w = f2h(v.w); l2.w = f2h(v.w - h2f(h.w));
    *(ushort4*)(hi + i) = h;
    *(ushort4*)(lo + i) = l2;
}

extern "C" void kernel_launch(void* const* d_in, const int* in_sizes, int n_in,
                              void* d_out, int out_size, void* d_ws, size_t ws_size,
                              hipStream_t stream) {
    (void)in_sizes; (void)n_in; (void)out_size; (void)ws_size;
    const float* skt = (const float*)d_in[0];
    const float* ref = (const float*)d_in[1];
    const float* Wa3 = (const float*)d_in[2];
    const float* ba3 = (const float*)d_in[3];
    const float* Wu3 = (const float*)d_in[4];
    const float* bu3 = (const float*)d_in[5];
    const float* Wa4 = (const float*)d_in[6];
    const float* ba4 = (const float*)d_in[7];
    const float* Wu4 = (const float*)d_in[8];
    const float* bu4 = (const float*)d_in[9];
    float* out = (float*)d_out;

    const i64 WHC = (i64)WH * CD;   // 1,048,576
    const i64 GM  = (i64)WH * WH;   // 16,777,216
    const i64 CC  = (i64)CD * CD;

    // workspace carve — total ~204.5 MB (proven-safe bound is ~212 MB)
    auto al = [](size_t x) { return (x + 255) & ~(size_t)255; };
    char* p = (char*)d_ws; size_t off = 0;
    auto carve = [&](size_t bytes) { void* r = p + off; off += al(bytes); return r; };
    float* Lb             = (float*)carve((size_t)GM * 4);              // 67.1 MB
    unsigned short* skthi = (unsigned short*)carve((size_t)4 * WHC * 2);
    unsigned short* sktlo = (unsigned short*)carve((size_t)4 * WHC * 2);
    unsigned short* refhi = (unsigned short*)carve((size_t)4 * WHC * 2);
    unsigned short* reflo = (unsigned short*)carve((size_t)4 * WHC * 2);
    unsigned short* ghi   = (unsigned short*)carve((size_t)4 * WHC * 2);
    unsigned short* glo   = (unsigned short*)carve((size_t)4 * WHC * 2); // 6x8.39 MB
    unsigned short* axthi = (unsigned short*)carve((size_t)4 * WHC * 2);
    unsigned short* axtlo = (unsigned short*)carve((size_t)4 * WHC * 2); // 16.8 MB
    float* ob             = (float*)carve((size_t)WH * 4);
    float* colM           = (float*)carve((size_t)WH * 4);
    float* colS           = (float*)carve((size_t)WH * 4);
    float2* partb         = (float2*)carve((size_t)64 * WH * 8);        // 2.1 MB
    unsigned short* Wthi  = (unsigned short*)carve((size_t)4 * CC * 2);
    unsigned short* Wtlo  = (unsigned short*)carve((size_t)4 * CC * 2);
    unsigned short* Ahi   = (unsigned short*)carve((size_t)GM * 2);     // 33.6 MB
    unsigned short* Alo   = (unsigned short*)carve((size_t)GM * 2);     // 33.6 MB

    dim3 thr(256), ttr(32, 8);
    k_trans<<<dim3(WH / 32, CD / 32, 4), ttr, 0, stream>>>(skt, skthi, sktlo, CD, WH, WHC, WHC);
    k_trans<<<dim3(WH / 32, CD / 32, 4), ttr, 0, stream>>>(ref, refhi, reflo, CD, WH, WHC, WHC);
    k_trans<<<dim3(CD / 32, CD / 32, 1), ttr, 0, stream>>>(Wa3, Wthi + 0 * CC, Wtlo + 0 * CC, CD, CD, 0, 0);
    k_trans<<<dim3(CD / 32, CD / 32, 1), ttr, 0, stream>>>(Wu3, Wthi + 1 * CC, Wtlo + 1 * CC, CD, CD, 0, 0);
    k_trans<<<dim3(CD / 32, CD / 32, 1), ttr, 0, stream>>>(Wa4, Wthi + 2 * CC, Wtlo + 2 * CC, CD, CD, 0, 0);
    k_trans<<<dim3(CD / 32, CD / 32, 1), ttr, 0, stream>>>(Wu4, Wthi + 3 * CC, Wtlo + 3 * CC, CD, CD, 0, 0);

    auto stage = [&](const unsigned short* shi, const unsigned short* slo,
                     const unsigned short* mhi, const unsigned short* mlo,
                     int widx, const float* ba, const float* bu, float* outf) {
        // ax = relu(msg @ Wa + ba), stored transposed as f16 split (all 4 batches)
        k_gemm<1><<<dim3(CD / 128, WH / 128, 4), thr, 0, stream>>>(
            mhi, mlo, CD, WHC, Wthi + (i64)widx * CC, Wtlo + (i64)widx * CC, CD, 0,
            nullptr, axthi, axtlo, WH, WHC, CD, ba, nullptr, nullptr);
        // r = relu(src @ Wu + bu) + src  -> outf (all 4 batches)
        k_gemm<2><<<dim3(CD / 128, WH / 128, 4), thr, 0, stream>>>(
            shi, slo, CD, WHC, Wthi + (i64)(widx + 1) * CC, Wtlo + (i64)(widx + 1) * CC, CD, 0,
            outf, nullptr, nullptr, CD, WHC, CD, bu, shi, slo);
        for (int b = 0; b < 4; ++b) {
            // logits -> Lb (f32)
            k_gemm<0><<<dim3(WH / 128, WH / 128, 1), thr, 0, stream>>>(
                shi + (i64)b * WHC, slo + (i64)b * WHC, CD, 0,
                mhi + (i64)b * WHC, mlo + (i64)b * WHC, CD, 0,
                Lb, nullptr, nullptr, WH, 0, CD, nullptr, nullptr, nullptr);
            k_rowstat<<<dim3(WH), thr, 0, stream>>>(Lb, ob);
            k_colpart<<<dim3(WH / 256, WH / 64, 1), thr, 0, stream>>>(Lb, ob, partb);
            k_colreduce<<<dim3(WH / 256), thr, 0, stream>>>(partb, colM, colS);
            k_writeA<<<dim3((unsigned)(GM / 2048)), thr, 0, stream>>>(Lb, ob, colM, colS, Ahi, Alo);
            // outf[b] += A @ ax   (split-K over 4 chunks, atomic f32)
            k_gemm<3><<<dim3(CD / 128, WH / 128, 4), thr, 0, stream>>>(
                Ahi, Alo, WH, 0, axthi + (i64)b * WHC, axtlo + (i64)b * WHC, WH, 0,
                outf + (i64)b * WHC, nullptr, nullptr, CD, 0, WH / 4, nullptr, nullptr, nullptr);
        }
    };

    // stage A: src = skt, msg = ref -> gen (accumulated in d_out)
    stage(skthi, sktlo, refhi, reflo, 0, ba3, bu3, out);
    k_mksplit<<<dim3((unsigned)(4 * WHC / 1024)), thr, 0, stream>>>(out, ghi, glo, 4 * WHC);
    // stage B: src = msg = gen -> final output (overwrites d_out)
    stage(ghi, glo, ghi, glo, 2, ba4, bu4, out);
}

// Round 5
// 1612.036 us; speedup vs baseline: 1.0153x; 1.0153x over previous
//
#include <hip/hip_runtime.h>
#include <cstdint>
#include <cstddef>

#define WH 4096
#define CD 256
#define SLAB 16
typedef long long i64;

typedef __attribute__((ext_vector_type(8))) _Float16 f16x8;
typedef __attribute__((ext_vector_type(4))) float f32x4;

#define AS1 __attribute__((address_space(1)))
#define AS3 __attribute__((address_space(3)))

__device__ __forceinline__ unsigned short f2h(float f) {
    _Float16 h = (_Float16)f;
    return __builtin_bit_cast(unsigned short, h);
}
__device__ __forceinline__ float h2f(unsigned short u) {
    return (float)__builtin_bit_cast(_Float16, u);
}
__device__ __forceinline__ void ld16_lds(const void* g, void* l) {
    __builtin_amdgcn_global_load_lds((AS1 void*)g, (AS3 void*)l, 16, 0, 0);
}

// -------- transpose f32 (src-stride CC) -> f16 split (dst-stride RR)
__global__ __launch_bounds__(256) void k_trans(const float* __restrict__ src,
                                               unsigned short* __restrict__ dhi,
                                               unsigned short* __restrict__ dlo,
                                               int RR, int CC, i64 ss, i64 ds) {
    __shared__ float t[32][33];
    const float* s = src + (i64)blockIdx.z * ss;
    const int c0 = blockIdx.x * 32, r0 = blockIdx.y * 32;
    const int tx = threadIdx.x, ty = threadIdx.y;
#pragma unroll
    for (int i = 0; i < 4; ++i)
        t[ty + i * 8][tx] = s[(i64)(r0 + ty + i * 8) * CC + c0 + tx];
    __syncthreads();
#pragma unroll
    for (int i = 0; i < 4; ++i) {
        const i64 idx = (i64)blockIdx.z * ds + (i64)(c0 + ty + i * 8) * RR + r0 + tx;
        const float v = t[tx][ty + i * 8];
        const unsigned short hi = f2h(v);
        dhi[idx] = hi;
        dlo[idx] = f2h(v - h2f(hi));
    }
}

// -------- NT GEMM, split-f16: C = (Ah+Al)(Bh+Bl)^T via 3 MFMA products.
// MODE 0: plain f32 store (logits -> Lb)
// MODE 1: bias+relu, store transposed f16-split (ax -> axt hi/lo)
// MODE 2: bias+relu, add split residual, f32 store (r -> outf)
template <int MODE>
__global__ __launch_bounds__(256) void k_gemm(
    const unsigned short* __restrict__ A, const unsigned short* __restrict__ A2, int lda, i64 sA,
    const unsigned short* __restrict__ B, const unsigned short* __restrict__ B2, int ldb, i64 sB,
    float* __restrict__ Cf, unsigned short* __restrict__ Chi, unsigned short* __restrict__ Clo,
    int ldc, i64 sC, int K,
    const float* __restrict__ bias,
    const unsigned short* __restrict__ addh, const unsigned short* __restrict__ addl) {
    __shared__ __align__(16) short lA[8192];
    __shared__ __align__(16) short lB[8192];
    const int z = blockIdx.z;
    A += (i64)z * sA; A2 += (i64)z * sA;
    B += (i64)z * sB; B2 += (i64)z * sB;

    const int tid = threadIdx.x;
    const int w = tid >> 6, l = tid & 63;
    const int wm = w >> 1, wn = w & 1;
    const int bm = blockIdx.y * 128, bn = blockIdx.x * 128;
    const int l15 = l & 15, lq = l >> 4;

    f32x4 acc[4][4] = {};

    for (int kt = 0; kt < K; kt += 32) {
        __syncthreads();
#pragma unroll
        for (int rr = 0; rr < 2; ++rr) {
            const int r = w + rr * 4;          // region 0..7
            const int kb = r >> 1, mh = r & 1;
            const int row = mh * 64 + l;
            const i64 ao = (i64)(bm + row) * lda + kt + kb * 8;
            const i64 bo = (i64)(bn + row) * ldb + kt + kb * 8;
            ld16_lds(A + ao, (char*)lA + r * 1024);
            ld16_lds(B + bo, (char*)lB + r * 1024);
            ld16_lds(A2 + ao, (char*)lA + 8192 + r * 1024);
            ld16_lds(B2 + bo, (char*)lB + 8192 + r * 1024);
        }
        __syncthreads();
        f16x8 ah[4], bh[4], al[4], bl[4];
#pragma unroll
        for (int i = 0; i < 4; ++i) {
            const int ia = (lq * 128 + wm * 64 + i * 16 + l15) * 8;
            const int ib = (lq * 128 + wn * 64 + i * 16 + l15) * 8;
            ah[i] = *(const f16x8*)(lA + ia);
            bh[i] = *(const f16x8*)(lB + ib);
            al[i] = *(const f16x8*)(lA + 4096 + ia);
            bl[i] = *(const f16x8*)(lB + 4096 + ib);
        }
#pragma unroll
        for (int i = 0; i < 4; ++i)
#pragma unroll
            for (int j = 0; j < 4; ++j) {
                acc[i][j] = __builtin_amdgcn_mfma_f32_16x16x32_f16(ah[i], bh[j], acc[i][j], 0, 0, 0);
                acc[i][j] = __builtin_amdgcn_mfma_f32_16x16x32_f16(ah[i], bl[j], acc[i][j], 0, 0, 0);
                acc[i][j] = __builtin_amdgcn_mfma_f32_16x16x32_f16(al[i], bh[j], acc[i][j], 0, 0, 0);
            }
    }

#pragma unroll
    for (int i = 0; i < 4; ++i)
#pragma unroll
        for (int j = 0; j < 4; ++j) {
            const int n = bn + wn * 64 + j * 16 + l15;
            const int m0 = bm + wm * 64 + i * 16 + lq * 4;
            float bv = 0.f;
            if constexpr (MODE == 1 || MODE == 2) bv = bias[n];
            if constexpr (MODE == 1) {
                unsigned short hv[4], lv[4];
#pragma unroll
                for (int r = 0; r < 4; ++r) {
                    const float v = fmaxf(acc[i][j][r] + bv, 0.f);
                    hv[r] = f2h(v);
                    lv[r] = f2h(v - h2f(hv[r]));
                }
                const i64 tb = (i64)z * sC + (i64)n * ldc + m0;
                *(ushort4*)(Chi + tb) = make_ushort4(hv[0], hv[1], hv[2], hv[3]);
                *(ushort4*)(Clo + tb) = make_ushort4(lv[0], lv[1], lv[2], lv[3]);
            } else {
#pragma unroll
                for (int r = 0; r < 4; ++r) {
                    float v = acc[i][j][r];
                    const i64 m = m0 + r;
                    const i64 idx = (i64)z * sC + m * ldc + n;
                    if constexpr (MODE == 0) {
                        Cf[idx] = v;
                    } else {  // MODE 2
                        v = fmaxf(v + bv, 0.f);
                        v += h2f(addh[idx]) + h2f(addl[idx]);
                        Cf[idx] = v;
                    }
                }
            }
        }
}

// -------- fused row stats + column partials over a 16-row slab.
// phase 1: o_i = rowmax + ln(rowsum exp) for the slab's rows
// phase 2: per-column online (max, expsum) of (L_ij - o_i) within the slab
__global__ __launch_bounds__(256) void k_stats(const float* __restrict__ L,
                                               float* __restrict__ o,
                                               float2* __restrict__ part) {
    __shared__ float os[SLAB];
    const int w = threadIdx.x >> 6, l = threadIdx.x & 63;
    const int r0 = blockIdx.x * SLAB;
    for (int rr = 0; rr < 4; ++rr) {
        const int row = r0 + w * 4 + rr;
        const float4* rp = (const float4*)(L + (i64)row * WH);
        float4 v[16];
#pragma unroll
        for (int k = 0; k < 16; ++k) v[k] = rp[l + 64 * k];
        float m = -3.4e38f;
#pragma unroll
        for (int k = 0; k < 16; ++k)
            m = fmaxf(m, fmaxf(fmaxf(v[k].x, v[k].y), fmaxf(v[k].z, v[k].w)));
#pragma unroll
        for (int off2 = 32; off2 >= 1; off2 >>= 1) m = fmaxf(m, __shfl_xor(m, off2));
        float s = 0.f;
#pragma unroll
        for (int k = 0; k < 16; ++k)
            s += __expf(v[k].x - m) + __expf(v[k].y - m) + __expf(v[k].z - m) + __expf(v[k].w - m);
#pragma unroll
        for (int off2 = 32; off2 >= 1; off2 >>= 1) s += __shfl_xor(s, off2);
        const float ov = m + __logf(s);
        if (l == 0) { os[w * 4 + rr] = ov; o[row] = ov; }
    }
    __syncthreads();
    const int t = threadIdx.x;
    float pm[16], ps[16];
#pragma unroll
    for (int k = 0; k < 16; ++k) { pm[k] = -3.4e38f; ps[k] = 0.f; }
    for (int r = 0; r < SLAB; ++r) {
        const float orow = os[r];
        const float4* rp = (const float4*)(L + (i64)(r0 + r) * WH);
#pragma unroll
        for (int g = 0; g < 4; ++g) {
            const float4 x = rp[g * 256 + t];
            const float xv[4] = {x.x, x.y, x.z, x.w};
#pragma unroll
            for (int e = 0; e < 4; ++e) {
                const int idx = g * 4 + e;
                const float v = xv[e] - orow;
                const float nm = fmaxf(pm[idx], v);
                ps[idx] = ps[idx] * __expf(pm[idx] - nm) + __expf(v - nm);
                pm[idx] = nm;
            }
        }
    }
#pragma unroll
    for (int g = 0; g < 4; ++g) {
        float2* pp = part + (i64)blockIdx.x * WH + g * 1024 + t * 4;
#pragma unroll
        for (int e = 0; e < 4; ++e) pp[e] = make_float2(pm[g * 4 + e], ps[g * 4 + e]);
    }
}

// -------- column reduce over 256 slab-partials -> (M_j, scale_j) with eps-clip semantics
__global__ __launch_bounds__(256) void k_colreduce(const float2* __restrict__ part,
                                                   float* __restrict__ colM,
                                                   float* __restrict__ colS) {
    const int j = blockIdx.x * 256 + threadIdx.x;
    float M = -3.4e38f, C = 0.f;
    for (int rb = 0; rb < WH / SLAB; ++rb) {
        const float2 p = part[(i64)rb * WH + j];
        const float nm = fmaxf(M, p.x);
        C = C * __expf(M - nm) + p.y * __expf(p.x - nm);
        M = nm;
    }
    const float lnS = M + __logf(C);
    colM[j] = M;
    // s_j = e^M * C; if s >= 1e-12: A = e^(x-M)/C; else A = e^(x-M) * e^(M + ln 1e12)
    colS[j] = (lnS >= -27.6310211159f) ? (1.f / C) : __expf(M + 27.6310211159f);
}

// -------- fused attention: out += [exp(L - o_i - M_j) * s_j] @ axt^T
// A computed on the fly from L (f32, staged via LDS), split f16 hi/lo in registers.
// grid (2, 32, 16): z = k-chunk of 256, atomicAdd f32 epilogue.
__global__ __launch_bounds__(256) void k_attn(
    const float* __restrict__ L, const float* __restrict__ o,
    const float* __restrict__ colM, const float* __restrict__ colS,
    const unsigned short* __restrict__ Bh, const unsigned short* __restrict__ Bl,
    float* __restrict__ Cf) {
    __shared__ __align__(16) float lL[4096];   // 16 KB: 128 rows x 32 k (crossed chunks)
    __shared__ __align__(16) short lBh[4096];  // 8 KB
    __shared__ __align__(16) short lBl[4096];  // 8 KB
    __shared__ float lM[256];
    __shared__ float lS[256];
    const int tid = threadIdx.x;
    const int w = tid >> 6, l = tid & 63;
    const int wm = w >> 1, wn = w & 1;
    const int bm = blockIdx.y * 128, bn = blockIdx.x * 128;
    const int l15 = l & 15, lq = l >> 4;
    const i64 koff = (i64)blockIdx.z * 256;

    lM[tid] = colM[koff + tid];
    lS[tid] = colS[koff + tid];
    float o4[4];
#pragma unroll
    for (int i = 0; i < 4; ++i) o4[i] = o[bm + wm * 64 + i * 16 + l15];

    f32x4 acc[4][4] = {};
    for (int kt = 0; kt < 256; kt += 32) {
        __syncthreads();
#pragma unroll
        for (int rr = 0; rr < 4; ++rr) {
            const int r = w + rr * 4;          // region 0..15 (1 KB each)
            const int kb2 = r >> 1, mh = r & 1;
            ld16_lds(L + (i64)(bm + mh * 64 + l) * WH + koff + kt + kb2 * 4,
                     (char*)lL + r * 1024);
        }
#pragma unroll
        for (int rr = 0; rr < 2; ++rr) {
            const int r = w + rr * 4;          // region 0..7
            const int kb = r >> 1, mh = r & 1;
            const i64 bo = (i64)(bn + mh * 64 + l) * WH + koff + kt + kb * 8;
            ld16_lds(Bh + bo, (char*)lBh + r * 1024);
            ld16_lds(Bl + bo, (char*)lBl + r * 1024);
        }
        __syncthreads();
        float mv[8], sv[8];
        *(float4*)(mv)     = *(const float4*)(lM + kt + lq * 8);
        *(float4*)(mv + 4) = *(const float4*)(lM + kt + lq * 8 + 4);
        *(float4*)(sv)     = *(const float4*)(lS + kt + lq * 8);
        *(float4*)(sv + 4) = *(const float4*)(lS + kt + lq * 8 + 4);
        f16x8 bh[4], bl[4];
#pragma unroll
        for (int j = 0; j < 4; ++j) {
            const int ib = (lq * 128 + wn * 64 + j * 16 + l15) * 8;
            bh[j] = *(const f16x8*)(lBh + ib);
            bl[j] = *(const f16x8*)(lBl + ib);
        }
#pragma unroll
        for (int i = 0; i < 4; ++i) {
            const int mrow = wm * 64 + i * 16 + l15;
            const float* lp = lL + lq * 1024 + mrow * 4;
            float xv[8];
            *(float4*)(xv)     = *(const float4*)(lp);
            *(float4*)(xv + 4) = *(const float4*)(lp + 512);
            const float oi = o4[i];
            f16x8 ah, al;
#pragma unroll
            for (int e = 0; e < 8; ++e) {
                const float a = __expf(xv[e] - oi - mv[e]) * sv[e];
                const _Float16 hh = (_Float16)a;
                ah[e] = hh;
                al[e] = (_Float16)(a - (float)hh);
            }
#pragma unroll
            for (int j = 0; j < 4; ++j) {
                acc[i][j] = __builtin_amdgcn_mfma_f32_16x16x32_f16(ah, bh[j], acc[i][j], 0, 0, 0);
                acc[i][j] = __builtin_amdgcn_mfma_f32_16x16x32_f16(ah, bl[j], acc[i][j], 0, 0, 0);
                acc[i][j] = __builtin_amdgcn_mfma_f32_16x16x32_f16(al, bh[j], acc[i][j], 0, 0, 0);
            }
        }
    }
#pragma unroll
    for (int i = 0; i < 4; ++i)
#pragma unroll
        for (int j = 0; j < 4; ++j) {
            const int n = bn + wn * 64 + j * 16 + l15;
            const int m0 = bm + wm * 64 + i * 16 + lq * 4;
#pragma unroll
            for (int r = 0; r < 4; ++r)
                atomicAdd(&Cf[(i64)(m0 + r) * CD + n], acc[i][j][r]);
        }
}

// -------- f32 -> (f16 hi, f16 lo) split
__global__ __launch_bounds__(256) void k_mksplit(const float* __restrict__ in,
                                                 unsigned short* __restrict__ hi,
                                                 unsigned short* __restrict__ lo, i64 n) {
    const i64 i = ((i64)blockIdx.x * 256 + threadIdx.x) * 4;
    if (i >= n) return;
    const float4 v = *(const float4*)(in + i);
    ushort4 h, l2;
    h.x = f2h(v.x); l2.x = f2h(v.x - h2f(h.x));
    h.y = f2h(v.y); l2.y = f2h(v.y - h2f(h.y));
    h.z = f2h(v.z); l2.z = f2h(v.z - h2f(h.z));
    h.w = f2h(v.w); l2.w = f2h(v.w - h2f(h.w));
    *(ushort4*)(hi + i) = h;
    *(ushort4*)(lo + i) = l2;
}

extern "C" void kernel_launch(void* const* d_in, const int* in_sizes, int n_in,
                              void* d_out, int out_size, void* d_ws, size_t ws_size,
                              hipStream_t stream) {
    (void)in_sizes; (void)n_in; (void)out_size; (void)ws_size;
    const float* skt = (const float*)d_in[0];
    const float* ref = (const float*)d_in[1];
    const float* Wa3 = (const float*)d_in[2];
    const float* ba3 = (const float*)d_in[3];
    const float* Wu3 = (const float*)d_in[4];
    const float* bu3 = (const float*)d_in[5];
    const float* Wa4 = (const float*)d_in[6];
    const float* ba4 = (const float*)d_in[7];
    const float* Wu4 = (const float*)d_in[8];
    const float* bu4 = (const float*)d_in[9];
    float* out = (float*)d_out;

    const i64 WHC = (i64)WH * CD;   // 1,048,576
    const i64 GM  = (i64)WH * WH;   // 16,777,216
    const i64 CC  = (i64)CD * CD;

    // workspace carve — total ~144 MB
    auto al = [](size_t x) { return (x + 255) & ~(size_t)255; };
    char* p = (char*)d_ws; size_t off = 0;
    auto carve = [&](size_t bytes) { void* r = p + off; off += al(bytes); return r; };
    float* Lb             = (float*)carve((size_t)GM * 4);              // 67.1 MB
    unsigned short* skthi = (unsigned short*)carve((size_t)4 * WHC * 2);
    unsigned short* sktlo = (unsigned short*)carve((size_t)4 * WHC * 2);
    unsigned short* refhi = (unsigned short*)carve((size_t)4 * WHC * 2);
    unsigned short* reflo = (unsigned short*)carve((size_t)4 * WHC * 2);
    unsigned short* ghi   = (unsigned short*)carve((size_t)4 * WHC * 2);
    unsigned short* glo   = (unsigned short*)carve((size_t)4 * WHC * 2); // 6x8.39 MB
    unsigned short* axthi = (unsigned short*)carve((size_t)4 * WHC * 2);
    unsigned short* axtlo = (unsigned short*)carve((size_t)4 * WHC * 2); // 16.8 MB
    float* ob             = (float*)carve((size_t)WH * 4);
    float* colM           = (float*)carve((size_t)WH * 4);
    float* colS           = (float*)carve((size_t)WH * 4);
    float2* partb         = (float2*)carve((size_t)(WH / SLAB) * WH * 8); // 8.39 MB
    unsigned short* Wthi  = (unsigned short*)carve((size_t)4 * CC * 2);
    unsigned short* Wtlo  = (unsigned short*)carve((size_t)4 * CC * 2);

    dim3 thr(256), ttr(32, 8);
    k_trans<<<dim3(WH / 32, CD / 32, 4), ttr, 0, stream>>>(skt, skthi, sktlo, CD, WH, WHC, WHC);
    k_trans<<<dim3(WH / 32, CD / 32, 4), ttr, 0, stream>>>(ref, refhi, reflo, CD, WH, WHC, WHC);
    k_trans<<<dim3(CD / 32, CD / 32, 1), ttr, 0, stream>>>(Wa3, Wthi + 0 * CC, Wtlo + 0 * CC, CD, CD, 0, 0);
    k_trans<<<dim3(CD / 32, CD / 32, 1), ttr, 0, stream>>>(Wu3, Wthi + 1 * CC, Wtlo + 1 * CC, CD, CD, 0, 0);
    k_trans<<<dim3(CD / 32, CD / 32, 1), ttr, 0, stream>>>(Wa4, Wthi + 2 * CC, Wtlo + 2 * CC, CD, CD, 0, 0);
    k_trans<<<dim3(CD / 32, CD / 32, 1), ttr, 0, stream>>>(Wu4, Wthi + 3 * CC, Wtlo + 3 * CC, CD, CD, 0, 0);

    auto stage = [&](const unsigned short* shi, const unsigned short* slo,
                     const unsigned short* mhi, const unsigned short* mlo,
                     int widx, const float* ba, const float* bu, float* outf) {
        // ax = relu(msg @ Wa + ba), stored transposed as f16 split (all 4 batches)
        k_gemm<1><<<dim3(CD / 128, WH / 128, 4), thr, 0, stream>>>(
            mhi, mlo, CD, WHC, Wthi + (i64)widx * CC, Wtlo + (i64)widx * CC, CD, 0,
            nullptr, axthi, axtlo, WH, WHC, CD, ba, nullptr, nullptr);
        // r = relu(src @ Wu + bu) + src  -> outf (all 4 batches)
        k_gemm<2><<<dim3(CD / 128, WH / 128, 4), thr, 0, stream>>>(
            shi, slo, CD, WHC, Wthi + (i64)(widx + 1) * CC, Wtlo + (i64)(widx + 1) * CC, CD, 0,
            outf, nullptr, nullptr, CD, WHC, CD, bu, shi, slo);
        for (int b = 0; b < 4; ++b) {
            // logits -> Lb (f32)
            k_gemm<0><<<dim3(WH / 128, WH / 128, 1), thr, 0, stream>>>(
                shi + (i64)b * WHC, slo + (i64)b * WHC, CD, 0,
                mhi + (i64)b * WHC, mlo + (i64)b * WHC, CD, 0,
                Lb, nullptr, nullptr, WH, 0, CD, nullptr, nullptr, nullptr);
            k_stats<<<dim3(WH / SLAB), thr, 0, stream>>>(Lb, ob, partb);
            k_colreduce<<<dim3(WH / 256), thr, 0, stream>>>(partb, colM, colS);
            // outf[b] += A(Lb) @ ax   (fused, split-K over 16 chunks, atomic f32)
            k_attn<<<dim3(CD / 128, WH / 128, 16), thr, 0, stream>>>(
                Lb, ob, colM, colS,
                axthi + (i64)b * WHC, axtlo + (i64)b * WHC, outf + (i64)b * WHC);
        }
    };

    // stage A: src = skt, msg = ref -> gen (accumulated in d_out)
    stage(skthi, sktlo, refhi, reflo, 0, ba3, bu3, out);
    k_mksplit<<<dim3((unsigned)(4 * WHC / 1024)), thr, 0, stream>>>(out, ghi, glo, 4 * WHC);
    // stage B: src = msg = gen -> final output (overwrites d_out)
    stage(ghi, glo, ghi, glo, 2, ba4, bu4, out);
}

// Round 7
// 1338.868 us; speedup vs baseline: 1.2225x; 1.2040x over previous
//
#include <hip/hip_runtime.h>
#include <cstdint>
#include <cstddef>

#define WH 4096
#define CD 256
typedef long long i64;

typedef __attribute__((ext_vector_type(8))) _Float16 f16x8;
typedef __attribute__((ext_vector_type(4))) float f32x4;

#define AS1 __attribute__((address_space(1)))
#define AS3 __attribute__((address_space(3)))

__device__ __forceinline__ unsigned short f2h(float f) {
    _Float16 h = (_Float16)f;
    return __builtin_bit_cast(unsigned short, h);
}
__device__ __forceinline__ float h2f(unsigned short u) {
    return (float)__builtin_bit_cast(_Float16, u);
}
__device__ __forceinline__ void ld16_lds(const void* g, void* l) {
    __builtin_amdgcn_global_load_lds((AS1 void*)g, (AS3 void*)l, 16, 0, 0);
}

// -------- transpose f32 (src-stride CC) -> f16 split (dst-stride RR)
__global__ __launch_bounds__(256) void k_trans(const float* __restrict__ src,
                                               unsigned short* __restrict__ dhi,
                                               unsigned short* __restrict__ dlo,
                                               int RR, int CC, i64 ss, i64 ds) {
    __shared__ float t[32][33];
    const float* s = src + (i64)blockIdx.z * ss;
    const int c0 = blockIdx.x * 32, r0 = blockIdx.y * 32;
    const int tx = threadIdx.x, ty = threadIdx.y;
#pragma unroll
    for (int i = 0; i < 4; ++i)
        t[ty + i * 8][tx] = s[(i64)(r0 + ty + i * 8) * CC + c0 + tx];
    __syncthreads();
#pragma unroll
    for (int i = 0; i < 4; ++i) {
        const i64 idx = (i64)blockIdx.z * ds + (i64)(c0 + ty + i * 8) * RR + r0 + tx;
        const float v = t[tx][ty + i * 8];
        const unsigned short hi = f2h(v);
        dhi[idx] = hi;
        dlo[idx] = f2h(v - h2f(hi));
    }
}

// -------- NT GEMM, split-f16: C = (Ah+Al)(Bh+Bl)^T via 3 MFMA products.
// MODE 0: plain f32 store (logits -> Lb)
// MODE 1: bias+relu, store transposed f16-split (ax -> axt hi/lo)
// MODE 2: bias+relu, add split residual, f32 store (r -> outf)
template <int MODE>
__global__ __launch_bounds__(256) void k_gemm(
    const unsigned short* __restrict__ A, const unsigned short* __restrict__ A2, int lda, i64 sA,
    const unsigned short* __restrict__ B, const unsigned short* __restrict__ B2, int ldb, i64 sB,
    float* __restrict__ Cf, unsigned short* __restrict__ Chi, unsigned short* __restrict__ Clo,
    int ldc, i64 sC, int K,
    const float* __restrict__ bias,
    const unsigned short* __restrict__ addh, const unsigned short* __restrict__ addl) {
    __shared__ __align__(16) short lA[8192];
    __shared__ __align__(16) short lB[8192];
    const int z = blockIdx.z;
    A += (i64)z * sA; A2 += (i64)z * sA;
    B += (i64)z * sB; B2 += (i64)z * sB;

    const int tid = threadIdx.x;
    const int w = tid >> 6, l = tid & 63;
    const int wm = w >> 1, wn = w & 1;
    const int bm = blockIdx.y * 128, bn = blockIdx.x * 128;
    const int l15 = l & 15, lq = l >> 4;

    f32x4 acc[4][4] = {};

    for (int kt = 0; kt < K; kt += 32) {
        __syncthreads();
#pragma unroll
        for (int rr = 0; rr < 2; ++rr) {
            const int r = w + rr * 4;          // region 0..7
            const int kb = r >> 1, mh = r & 1;
            const int row = mh * 64 + l;
            const i64 ao = (i64)(bm + row) * lda + kt + kb * 8;
            const i64 bo = (i64)(bn + row) * ldb + kt + kb * 8;
            ld16_lds(A + ao, (char*)lA + r * 1024);
            ld16_lds(B + bo, (char*)lB + r * 1024);
            ld16_lds(A2 + ao, (char*)lA + 8192 + r * 1024);
            ld16_lds(B2 + bo, (char*)lB + 8192 + r * 1024);
        }
        __syncthreads();
        f16x8 ah[4], bh[4], al[4], bl[4];
#pragma unroll
        for (int i = 0; i < 4; ++i) {
            const int ia = (lq * 128 + wm * 64 + i * 16 + l15) * 8;
            const int ib = (lq * 128 + wn * 64 + i * 16 + l15) * 8;
            ah[i] = *(const f16x8*)(lA + ia);
            bh[i] = *(const f16x8*)(lB + ib);
            al[i] = *(const f16x8*)(lA + 4096 + ia);
            bl[i] = *(const f16x8*)(lB + 4096 + ib);
        }
#pragma unroll
        for (int i = 0; i < 4; ++i)
#pragma unroll
            for (int j = 0; j < 4; ++j) {
                acc[i][j] = __builtin_amdgcn_mfma_f32_16x16x32_f16(ah[i], bh[j], acc[i][j], 0, 0, 0);
                acc[i][j] = __builtin_amdgcn_mfma_f32_16x16x32_f16(ah[i], bl[j], acc[i][j], 0, 0, 0);
                acc[i][j] = __builtin_amdgcn_mfma_f32_16x16x32_f16(al[i], bh[j], acc[i][j], 0, 0, 0);
            }
    }

#pragma unroll
    for (int i = 0; i < 4; ++i)
#pragma unroll
        for (int j = 0; j < 4; ++j) {
            const int n = bn + wn * 64 + j * 16 + l15;
            const int m0 = bm + wm * 64 + i * 16 + lq * 4;
            float bv = 0.f;
            if constexpr (MODE == 1 || MODE == 2) bv = bias[n];
            if constexpr (MODE == 1) {
                unsigned short hv[4], lv[4];
#pragma unroll
                for (int r = 0; r < 4; ++r) {
                    const float v = fmaxf(acc[i][j][r] + bv, 0.f);
                    hv[r] = f2h(v);
                    lv[r] = f2h(v - h2f(hv[r]));
                }
                const i64 tb = (i64)z * sC + (i64)n * ldc + m0;
                *(ushort4*)(Chi + tb) = make_ushort4(hv[0], hv[1], hv[2], hv[3]);
                *(ushort4*)(Clo + tb) = make_ushort4(lv[0], lv[1], lv[2], lv[3]);
            } else {
#pragma unroll
                for (int r = 0; r < 4; ++r) {
                    float v = acc[i][j][r];
                    const i64 idx = (i64)z * sC + (i64)(m0 + r) * ldc + n;
                    if constexpr (MODE == 0) {
                        Cf[idx] = v;
                    } else {  // MODE 2
                        v = fmaxf(v + bv, 0.f);
                        v += h2f(addh[idx]) + h2f(addl[idx]);
                        Cf[idx] = v;
                    }
                }
            }
        }
}

// -------- row stats: o_i = rowmax + ln(rowsum exp)   [round-4 verified]
__global__ __launch_bounds__(256) void k_rowstat(const float* __restrict__ Lp,
                                                 float* __restrict__ o) {
    const i64 row = blockIdx.x;
    const float4* rp = (const float4*)(Lp + row * WH);
    const int t = threadIdx.x;
    float4 v[4];
#pragma unroll
    for (int k = 0; k < 4; ++k) v[k] = rp[t + 256 * k];
    float m = -3.4e38f;
#pragma unroll
    for (int k = 0; k < 4; ++k)
        m = fmaxf(m, fmaxf(fmaxf(v[k].x, v[k].y), fmaxf(v[k].z, v[k].w)));
#pragma unroll
    for (int off = 32; off >= 1; off >>= 1) m = fmaxf(m, __shfl_xor(m, off));
    __shared__ float red[4];
    if ((t & 63) == 0) red[t >> 6] = m;
    __syncthreads();
    m = fmaxf(fmaxf(red[0], red[1]), fmaxf(red[2], red[3]));
    float ssum = 0.f;
#pragma unroll
    for (int k = 0; k < 4; ++k)
        ssum += __expf(v[k].x - m) + __expf(v[k].y - m) + __expf(v[k].z - m) + __expf(v[k].w - m);
#pragma unroll
    for (int off = 32; off >= 1; off >>= 1) ssum += __shfl_xor(ssum, off);
    __syncthreads();
    if ((t & 63) == 0) red[t >> 6] = ssum;
    __syncthreads();
    if (t == 0) o[row] = m + __logf(red[0] + red[1] + red[2] + red[3]);
}

// -------- column partials: per (64-row block, col) online (max, expsum) of L - o_i  [round-4 verified]
__global__ __launch_bounds__(256) void k_colpart(const float* __restrict__ L,
                                                 const float* __restrict__ o,
                                                 float2* __restrict__ part) {
    const int j = blockIdx.x * 256 + threadIdx.x;
    const int r0 = blockIdx.y * 64;
    float pm = -3.4e38f, ps = 0.f;
    for (int r = 0; r < 64; ++r) {
        const float x = L[(i64)(r0 + r) * WH + j] - o[r0 + r];
        if (x > pm) { ps *= __expf(pm - x); pm = x; }
        ps += __expf(x - pm);
    }
    part[(i64)blockIdx.y * WH + j] = make_float2(pm, ps);
}

// -------- column reduce -> (M_j, scale_j) with eps-clip semantics  [round-4 verified]
__global__ __launch_bounds__(256) void k_colreduce(const float2* __restrict__ part,
                                                   float* __restrict__ colM,
                                                   float* __restrict__ colS) {
    const int j = blockIdx.x * 256 + threadIdx.x;
    float M = -3.4e38f, C = 0.f;
    for (int rb = 0; rb < 64; ++rb) {
        const float2 p = part[(i64)rb * WH + j];
        if (p.x > M) { C *= __expf(M - p.x); M = p.x; }
        C += p.y * __expf(p.x - M);
    }
    const float lnS = M + __logf(C);
    colM[j] = M;
    // s_j = e^M * C; if s >= 1e-12: A = e^(x-M)/C; else A = e^(x-M) * e^(M + ln 1e12)
    colS[j] = (lnS >= -27.6310211159f) ? (1.f / C) : __expf(M + 27.6310211159f);
}

// -------- fused attention: P[z] = [exp(L - o_i - M_j) * s_j]_{k-chunk z} @ axt^T
// A computed on the fly from L (f32 via LDS), split f16 hi/lo in registers.
// grid (2, 32, 16): z = k-chunk of 256; plain f32 partial stores (no atomics).
__global__ __launch_bounds__(256) void k_attn(
    const float* __restrict__ L, const float* __restrict__ o,
    const float* __restrict__ colM, const float* __restrict__ colS,
    const unsigned short* __restrict__ Bh, const unsigned short* __restrict__ Bl,
    float* __restrict__ Pw) {
    __shared__ __align__(16) float lL[4096];   // 16 KB: 128 rows x 32 k (crossed chunks)
    __shared__ __align__(16) short lBh[4096];  // 8 KB
    __shared__ __align__(16) short lBl[4096];  // 8 KB
    __shared__ float lM[256];
    __shared__ float lS[256];
    const int tid = threadIdx.x;
    const int w = tid >> 6, l = tid & 63;
    const int wm = w >> 1, wn = w & 1;
    const int bm = blockIdx.y * 128, bn = blockIdx.x * 128;
    const int l15 = l & 15, lq = l >> 4;
    const i64 koff = (i64)blockIdx.z * 256;

    lM[tid] = colM[koff + tid];
    lS[tid] = colS[koff + tid];
    float o4[4];
#pragma unroll
    for (int i = 0; i < 4; ++i) o4[i] = o[bm + wm * 64 + i * 16 + l15];

    f32x4 acc[4][4] = {};
    for (int kt = 0; kt < 256; kt += 32) {
        __syncthreads();
#pragma unroll
        for (int rr = 0; rr < 4; ++rr) {
            const int r = w + rr * 4;          // region 0..15 (1 KB each)
            const int kb2 = r >> 1, mh = r & 1;
            ld16_lds(L + (i64)(bm + mh * 64 + l) * WH + koff + kt + kb2 * 4,
                     (char*)lL + r * 1024);
        }
#pragma unroll
        for (int rr = 0; rr < 2; ++rr) {
            const int r = w + rr * 4;          // region 0..7
            const int kb = r >> 1, mh = r & 1;
            const i64 bo = (i64)(bn + mh * 64 + l) * WH + koff + kt + kb * 8;
            ld16_lds(Bh + bo, (char*)lBh + r * 1024);
            ld16_lds(Bl + bo, (char*)lBl + r * 1024);
        }
        __syncthreads();
        float mv[8], sv[8];
        *(float4*)(mv)     = *(const float4*)(lM + kt + lq * 8);
        *(float4*)(mv + 4) = *(const float4*)(lM + kt + lq * 8 + 4);
        *(float4*)(sv)     = *(const float4*)(lS + kt + lq * 8);
        *(float4*)(sv + 4) = *(const float4*)(lS + kt + lq * 8 + 4);
        f16x8 bh[4], bl[4];
#pragma unroll
        for (int j = 0; j < 4; ++j) {
            const int ib = (lq * 128 + wn * 64 + j * 16 + l15) * 8;
            bh[j] = *(const f16x8*)(lBh + ib);
            bl[j] = *(const f16x8*)(lBl + ib);
        }
#pragma unroll
        for (int i = 0; i < 4; ++i) {
            const int mrow = wm * 64 + i * 16 + l15;
            const float* lp = lL + lq * 1024 + mrow * 4;
            float xv[8];
            *(float4*)(xv)     = *(const float4*)(lp);
            *(float4*)(xv + 4) = *(const float4*)(lp + 512);
            const float oi = o4[i];
            f16x8 ah, al;
#pragma unroll
            for (int e = 0; e < 8; ++e) {
                const float a = __expf(xv[e] - oi - mv[e]) * sv[e];
                const _Float16 hh = (_Float16)a;
                ah[e] = hh;
                al[e] = (_Float16)(a - (float)hh);
            }
#pragma unroll
            for (int j = 0; j < 4; ++j) {
                acc[i][j] = __builtin_amdgcn_mfma_f32_16x16x32_f16(ah, bh[j], acc[i][j], 0, 0, 0);
                acc[i][j] = __builtin_amdgcn_mfma_f32_16x16x32_f16(ah, bl[j], acc[i][j], 0, 0, 0);
                acc[i][j] = __builtin_amdgcn_mfma_f32_16x16x32_f16(al, bh[j], acc[i][j], 0, 0, 0);
            }
        }
    }
    float* P = Pw + (i64)blockIdx.z * ((i64)WH * CD);
#pragma unroll
    for (int i = 0; i < 4; ++i)
#pragma unroll
        for (int j = 0; j < 4; ++j) {
            const int n = bn + wn * 64 + j * 16 + l15;
            const int m0 = bm + wm * 64 + i * 16 + lq * 4;
#pragma unroll
            for (int r = 0; r < 4; ++r)
                P[(i64)(m0 + r) * CD + n] = acc[i][j][r];
        }
}

// -------- reduce 16 split-K partials into outf (which holds r)
__global__ __launch_bounds__(256) void k_red(const float* __restrict__ Pw,
                                             float* __restrict__ outp) {
    const i64 i = ((i64)blockIdx.x * 256 + threadIdx.x) * 4;
    float4 a = *(const float4*)(outp + i);
#pragma unroll
    for (int z = 0; z < 16; ++z) {
        const float4 p = *(const float4*)(Pw + (i64)z * ((i64)WH * CD) + i);
        a.x += p.x; a.y += p.y; a.z += p.z; a.w += p.w;
    }
    *(float4*)(outp + i) = a;
}

// -------- f32 -> (f16 hi, f16 lo) split
__global__ __launch_bounds__(256) void k_mksplit(const float* __restrict__ in,
                                                 unsigned short* __restrict__ hi,
                                                 unsigned short* __restrict__ lo, i64 n) {
    const i64 i = ((i64)blockIdx.x * 256 + threadIdx.x) * 4;
    if (i >= n) return;
    const float4 v = *(const float4*)(in + i);
    ushort4 h, l2;
    h.x = f2h(v.x); l2.x = f2h(v.x - h2f(h.x));
    h.y = f2h(v.y); l2.y = f2h(v.y - h2f(h.y));
    h.z = f2h(v.z); l2.z = f2h(v.z - h2f(h.z));
    h.w = f2h(v.w); l2.w = f2h(v.w - h2f(h.w));
    *(ushort4*)(hi + i) = h;
    *(ushort4*)(lo + i) = l2;
}

extern "C" void kernel_launch(void* const* d_in, const int* in_sizes, int n_in,
                              void* d_out, int out_size, void* d_ws, size_t ws_size,
                              hipStream_t stream) {
    (void)in_sizes; (void)n_in; (void)out_size; (void)ws_size;
    const float* skt = (const float*)d_in[0];
    const float* ref = (const float*)d_in[1];
    const float* Wa3 = (const float*)d_in[2];
    const float* ba3 = (const float*)d_in[3];
    const float* Wu3 = (const float*)d_in[4];
    const float* bu3 = (const float*)d_in[5];
    const float* Wa4 = (const float*)d_in[6];
    const float* ba4 = (const float*)d_in[7];
    const float* Wu4 = (const float*)d_in[8];
    const float* bu4 = (const float*)d_in[9];
    float* out = (float*)d_out;

    const i64 WHC = (i64)WH * CD;   // 1,048,576
    const i64 GM  = (i64)WH * WH;   // 16,777,216
    const i64 CC  = (i64)CD * CD;

    // workspace carve — total ~204.5 MB (exact footprint proven in round 4)
    auto al = [](size_t x) { return (x + 255) & ~(size_t)255; };
    char* p = (char*)d_ws; size_t off = 0;
    auto carve = [&](size_t bytes) { void* r = p + off; off += al(bytes); return r; };
    float* Lb             = (float*)carve((size_t)GM * 4);               // 67.1 MB
    unsigned short* skthi = (unsigned short*)carve((size_t)4 * WHC * 2);
    unsigned short* sktlo = (unsigned short*)carve((size_t)4 * WHC * 2);
    unsigned short* refhi = (unsigned short*)carve((size_t)4 * WHC * 2);
    unsigned short* reflo = (unsigned short*)carve((size_t)4 * WHC * 2);
    unsigned short* ghi   = (unsigned short*)carve((size_t)4 * WHC * 2);
    unsigned short* glo   = (unsigned short*)carve((size_t)4 * WHC * 2); // 6x8.39 MB
    unsigned short* axthi = (unsigned short*)carve((size_t)4 * WHC * 2);
    unsigned short* axtlo = (unsigned short*)carve((size_t)4 * WHC * 2); // 16.8 MB
    float* ob             = (float*)carve((size_t)WH * 4);
    float* colM           = (float*)carve((size_t)WH * 4);
    float* colS           = (float*)carve((size_t)WH * 4);
    float2* partb         = (float2*)carve((size_t)64 * WH * 8);         // 2.1 MB
    unsigned short* Wthi  = (unsigned short*)carve((size_t)4 * CC * 2);
    unsigned short* Wtlo  = (unsigned short*)carve((size_t)4 * CC * 2);
    float* Pw             = (float*)carve((size_t)16 * WHC * 4);         // 67.1 MB

    dim3 thr(256), ttr(32, 8);
    k_trans<<<dim3(WH / 32, CD / 32, 4), ttr, 0, stream>>>(skt, skthi, sktlo, CD, WH, WHC, WHC);
    k_trans<<<dim3(WH / 32, CD / 32, 4), ttr, 0, stream>>>(ref, refhi, reflo, CD, WH, WHC, WHC);
    k_trans<<<dim3(CD / 32, CD / 32, 1), ttr, 0, stream>>>(Wa3, Wthi + 0 * CC, Wtlo + 0 * CC, CD, CD, 0, 0);
    k_trans<<<dim3(CD / 32, CD / 32, 1), ttr, 0, stream>>>(Wu3, Wthi + 1 * CC, Wtlo + 1 * CC, CD, CD, 0, 0);
    k_trans<<<dim3(CD / 32, CD / 32, 1), ttr, 0, stream>>>(Wa4, Wthi + 2 * CC, Wtlo + 2 * CC, CD, CD, 0, 0);
    k_trans<<<dim3(CD / 32, CD / 32, 1), ttr, 0, stream>>>(Wu4, Wthi + 3 * CC, Wtlo + 3 * CC, CD, CD, 0, 0);

    auto stage = [&](const unsigned short* shi, const unsigned short* slo,
                     const unsigned short* mhi, const unsigned short* mlo,
                     int widx, const float* ba, const float* bu, float* outf) {
        // ax = relu(msg @ Wa + ba), stored transposed as f16 split (all 4 batches)
        k_gemm<1><<<dim3(CD / 128, WH / 128, 4), thr, 0, stream>>>(
            mhi, mlo, CD, WHC, Wthi + (i64)widx * CC, Wtlo + (i64)widx * CC, CD, 0,
            nullptr, axthi, axtlo, WH, WHC, CD, ba, nullptr, nullptr);
        // r = relu(src @ Wu + bu) + src  -> outf (all 4 batches)
        k_gemm<2><<<dim3(CD / 128, WH / 128, 4), thr, 0, stream>>>(
            shi, slo, CD, WHC, Wthi + (i64)(widx + 1) * CC, Wtlo + (i64)(widx + 1) * CC, CD, 0,
            outf, nullptr, nullptr, CD, WHC, CD, bu, shi, slo);
        for (int b = 0; b < 4; ++b) {
            // logits -> Lb (f32)
            k_gemm<0><<<dim3(WH / 128, WH / 128, 1), thr, 0, stream>>>(
                shi + (i64)b * WHC, slo + (i64)b * WHC, CD, 0,
                mhi + (i64)b * WHC, mlo + (i64)b * WHC, CD, 0,
                Lb, nullptr, nullptr, WH, 0, CD, nullptr, nullptr, nullptr);
            k_rowstat<<<dim3(WH), thr, 0, stream>>>(Lb, ob);
            k_colpart<<<dim3(WH / 256, WH / 64, 1), thr, 0, stream>>>(Lb, ob, partb);
            k_colreduce<<<dim3(WH / 256), thr, 0, stream>>>(partb, colM, colS);
            // P[z] = A(Lb)_chunk @ ax (split-K 16, plain stores)
            k_attn<<<dim3(CD / 128, WH / 128, 16), thr, 0, stream>>>(
                Lb, ob, colM, colS,
                axthi + (i64)b * WHC, axtlo + (i64)b * WHC, Pw);
            // outf[b] += sum_z P[z]
            k_red<<<dim3((unsigned)(WHC / 1024)), thr, 0, stream>>>(Pw, outf + (i64)b * WHC);
        }
    };

    // stage A: src = skt, msg = ref -> gen (accumulated in d_out)
    stage(skthi, sktlo, refhi, reflo, 0, ba3, bu3, out);
    k_mksplit<<<dim3((unsigned)(4 * WHC / 1024)), thr, 0, stream>>>(out, ghi, glo, 4 * WHC);
    // stage B: src = msg = gen -> final output (overwrites d_out)
    stage(ghi, glo, ghi, glo, 2, ba4, bu4, out);
}

// Round 8
// 1208.006 us; speedup vs baseline: 1.3549x; 1.1083x over previous
//
#include <hip/hip_runtime.h>
#include <cstdint>
#include <cstddef>

#define WH 4096
#define CD 256
typedef long long i64;

typedef __attribute__((ext_vector_type(8))) _Float16 f16x8;
typedef __attribute__((ext_vector_type(4))) float f32x4;

#define AS1 __attribute__((address_space(1)))
#define AS3 __attribute__((address_space(3)))

__device__ __forceinline__ unsigned short f2h(float f) {
    _Float16 h = (_Float16)f;
    return __builtin_bit_cast(unsigned short, h);
}
__device__ __forceinline__ float h2f(unsigned short u) {
    return (float)__builtin_bit_cast(_Float16, u);
}
__device__ __forceinline__ void ld16_lds(const void* g, void* l) {
    __builtin_amdgcn_global_load_lds((AS1 void*)g, (AS3 void*)l, 16, 0, 0);
}

// -------- transpose f32 (src-stride CC) -> f16 split (dst-stride RR)
__global__ __launch_bounds__(256) void k_trans(const float* __restrict__ src,
                                               unsigned short* __restrict__ dhi,
                                               unsigned short* __restrict__ dlo,
                                               int RR, int CC, i64 ss, i64 ds) {
    __shared__ float t[32][33];
    const float* s = src + (i64)blockIdx.z * ss;
    const int c0 = blockIdx.x * 32, r0 = blockIdx.y * 32;
    const int tx = threadIdx.x, ty = threadIdx.y;
#pragma unroll
    for (int i = 0; i < 4; ++i)
        t[ty + i * 8][tx] = s[(i64)(r0 + ty + i * 8) * CC + c0 + tx];
    __syncthreads();
#pragma unroll
    for (int i = 0; i < 4; ++i) {
        const i64 idx = (i64)blockIdx.z * ds + (i64)(c0 + ty + i * 8) * RR + r0 + tx;
        const float v = t[tx][ty + i * 8];
        const unsigned short hi = f2h(v);
        dhi[idx] = hi;
        dlo[idx] = f2h(v - h2f(hi));
    }
}

// -------- NT GEMM, split-f16: C = (Ah+Al)(Bh+Bl)^T via 3 MFMA products.
// MODE 0: f32 store (logits -> Lb) + fused per-block ROW stat partials (max,expsum over 128 cols)
// MODE 1: bias+relu, store transposed f16-split (ax -> axt hi/lo)
// MODE 2: bias+relu, add split residual, f32 store (r -> outf)
template <int MODE>
__global__ __launch_bounds__(256) void k_gemm(
    const unsigned short* __restrict__ A, const unsigned short* __restrict__ A2, int lda, i64 sA,
    const unsigned short* __restrict__ B, const unsigned short* __restrict__ B2, int ldb, i64 sB,
    float* __restrict__ Cf, unsigned short* __restrict__ Chi, unsigned short* __restrict__ Clo,
    int ldc, i64 sC, int K,
    const float* __restrict__ bias,
    const unsigned short* __restrict__ addh, const unsigned short* __restrict__ addl,
    float2* __restrict__ rowP) {
    __shared__ __align__(16) short lA[8192];
    __shared__ __align__(16) short lB[8192];
    __shared__ float2 redp[2][128];
    const int z = blockIdx.z;
    A += (i64)z * sA; A2 += (i64)z * sA;
    B += (i64)z * sB; B2 += (i64)z * sB;

    const int tid = threadIdx.x;
    const int w = tid >> 6, l = tid & 63;
    const int wm = w >> 1, wn = w & 1;
    const int bm = blockIdx.y * 128, bn = blockIdx.x * 128;
    const int l15 = l & 15, lq = l >> 4;

    f32x4 acc[4][4] = {};

    for (int kt = 0; kt < K; kt += 32) {
        __syncthreads();
#pragma unroll
        for (int rr = 0; rr < 2; ++rr) {
            const int r = w + rr * 4;          // region 0..7
            const int kb = r >> 1, mh = r & 1;
            const int row = mh * 64 + l;
            const i64 ao = (i64)(bm + row) * lda + kt + kb * 8;
            const i64 bo = (i64)(bn + row) * ldb + kt + kb * 8;
            ld16_lds(A + ao, (char*)lA + r * 1024);
            ld16_lds(B + bo, (char*)lB + r * 1024);
            ld16_lds(A2 + ao, (char*)lA + 8192 + r * 1024);
            ld16_lds(B2 + bo, (char*)lB + 8192 + r * 1024);
        }
        __syncthreads();
        f16x8 ah[4], bh[4], al[4], bl[4];
#pragma unroll
        for (int i = 0; i < 4; ++i) {
            const int ia = (lq * 128 + wm * 64 + i * 16 + l15) * 8;
            const int ib = (lq * 128 + wn * 64 + i * 16 + l15) * 8;
            ah[i] = *(const f16x8*)(lA + ia);
            bh[i] = *(const f16x8*)(lB + ib);
            al[i] = *(const f16x8*)(lA + 4096 + ia);
            bl[i] = *(const f16x8*)(lB + 4096 + ib);
        }
#pragma unroll
        for (int i = 0; i < 4; ++i)
#pragma unroll
            for (int j = 0; j < 4; ++j) {
                acc[i][j] = __builtin_amdgcn_mfma_f32_16x16x32_f16(ah[i], bh[j], acc[i][j], 0, 0, 0);
                acc[i][j] = __builtin_amdgcn_mfma_f32_16x16x32_f16(ah[i], bl[j], acc[i][j], 0, 0, 0);
                acc[i][j] = __builtin_amdgcn_mfma_f32_16x16x32_f16(al[i], bh[j], acc[i][j], 0, 0, 0);
            }
    }

#pragma unroll
    for (int i = 0; i < 4; ++i)
#pragma unroll
        for (int j = 0; j < 4; ++j) {
            const int n = bn + wn * 64 + j * 16 + l15;
            const int m0 = bm + wm * 64 + i * 16 + lq * 4;
            float bv = 0.f;
            if constexpr (MODE == 1 || MODE == 2) bv = bias[n];
            if constexpr (MODE == 1) {
                unsigned short hv[4], lv[4];
#pragma unroll
                for (int r = 0; r < 4; ++r) {
                    const float v = fmaxf(acc[i][j][r] + bv, 0.f);
                    hv[r] = f2h(v);
                    lv[r] = f2h(v - h2f(hv[r]));
                }
                const i64 tb = (i64)z * sC + (i64)n * ldc + m0;
                *(ushort4*)(Chi + tb) = make_ushort4(hv[0], hv[1], hv[2], hv[3]);
                *(ushort4*)(Clo + tb) = make_ushort4(lv[0], lv[1], lv[2], lv[3]);
            } else {
#pragma unroll
                for (int r = 0; r < 4; ++r) {
                    float v = acc[i][j][r];
                    const i64 idx = (i64)z * sC + (i64)(m0 + r) * ldc + n;
                    if constexpr (MODE == 0) {
                        Cf[idx] = v;
                    } else {  // MODE 2
                        v = fmaxf(v + bv, 0.f);
                        v += h2f(addh[idx]) + h2f(addl[idx]);
                        Cf[idx] = v;
                    }
                }
            }
        }

    if constexpr (MODE == 0) {
        // ---- fused row partials: (max, expsum) over this block's 128 cols, per row.
        // Row m0+r values live at cols j*16 (frag) x l15 (lane) for this warp's wn half.
        float rm[16], rs[16];
#pragma unroll
        for (int i = 0; i < 4; ++i)
#pragma unroll
            for (int r = 0; r < 4; ++r) {
                float m = fmaxf(fmaxf(acc[i][0][r], acc[i][1][r]), fmaxf(acc[i][2][r], acc[i][3][r]));
                m = fmaxf(m, __shfl_xor(m, 1));
                m = fmaxf(m, __shfl_xor(m, 2));
                m = fmaxf(m, __shfl_xor(m, 4));
                m = fmaxf(m, __shfl_xor(m, 8));
                rm[i * 4 + r] = m;
                float s = __expf(acc[i][0][r] - m) + __expf(acc[i][1][r] - m)
                        + __expf(acc[i][2][r] - m) + __expf(acc[i][3][r] - m);
                s += __shfl_xor(s, 1); s += __shfl_xor(s, 2);
                s += __shfl_xor(s, 4); s += __shfl_xor(s, 8);
                rs[i * 4 + r] = s;
            }
        __syncthreads();
        if (l15 == 0) {
#pragma unroll
            for (int i = 0; i < 4; ++i)
#pragma unroll
                for (int r = 0; r < 4; ++r)
                    redp[wn][wm * 64 + i * 16 + lq * 4 + r] = make_float2(rm[i * 4 + r], rs[i * 4 + r]);
        }
        __syncthreads();
        if (tid < 128) {
            const float2 a = redp[0][tid], b = redp[1][tid];
            const float m = fmaxf(a.x, b.x);
            const float s = a.y * __expf(a.x - m) + b.y * __expf(b.x - m);
            rowP[(i64)blockIdx.x * WH + bm + tid] = make_float2(m, s);
        }
    }
}

// -------- merge 32 row partials -> o_i = rowmax + ln(rowsum exp)
__global__ __launch_bounds__(256) void k_finrow(const float2* __restrict__ rowP,
                                                float* __restrict__ o) {
    const int j = blockIdx.x * 256 + threadIdx.x;
    float M = -3.4e38f, S = 0.f;
    for (int x = 0; x < 32; ++x) {
        const float2 p = rowP[(i64)x * WH + j];
        const float nm = fmaxf(M, p.x);
        S = S * __expf(M - nm) + p.y * __expf(p.x - nm);
        M = nm;
    }
    o[j] = M + __logf(S);
}

// -------- column partials: per (64-row block, col) online (max, expsum) of L - o_i  [verified]
__global__ __launch_bounds__(256) void k_colpart(const float* __restrict__ L,
                                                 const float* __restrict__ o,
                                                 float2* __restrict__ part) {
    const int j = blockIdx.x * 256 + threadIdx.x;
    const int r0 = blockIdx.y * 64;
    float pm = -3.4e38f, ps = 0.f;
    for (int r = 0; r < 64; ++r) {
        const float x = L[(i64)(r0 + r) * WH + j] - o[r0 + r];
        if (x > pm) { ps *= __expf(pm - x); pm = x; }
        ps += __expf(x - pm);
    }
    part[(i64)blockIdx.y * WH + j] = make_float2(pm, ps);
}

// -------- column reduce -> (M_j, scale_j) with eps-clip semantics  [verified]
__global__ __launch_bounds__(256) void k_colreduce(const float2* __restrict__ part,
                                                   float* __restrict__ colM,
                                                   float* __restrict__ colS) {
    const int j = blockIdx.x * 256 + threadIdx.x;
    float M = -3.4e38f, C = 0.f;
    for (int rb = 0; rb < 64; ++rb) {
        const float2 p = part[(i64)rb * WH + j];
        if (p.x > M) { C *= __expf(M - p.x); M = p.x; }
        C += p.y * __expf(p.x - M);
    }
    const float lnS = M + __logf(C);
    colM[j] = M;
    // s_j = e^M * C; if s >= 1e-12: A = e^(x-M)/C; else A = e^(x-M) * e^(M + ln 1e12)
    colS[j] = (lnS >= -27.6310211159f) ? (1.f / C) : __expf(M + 27.6310211159f);
}

// -------- fused attention: P[z] = [exp(L - o_i - M_j) * s_j]_{k-chunk z} @ axt^T
// A computed on the fly from L (f32 via LDS), split f16 hi/lo in registers.
// grid (2, 32, 8): z = k-chunk of 512; plain f32 partial stores (no atomics).
__global__ __launch_bounds__(256) void k_attn(
    const float* __restrict__ L, const float* __restrict__ o,
    const float* __restrict__ colM, const float* __restrict__ colS,
    const unsigned short* __restrict__ Bh, const unsigned short* __restrict__ Bl,
    float* __restrict__ Pw) {
    __shared__ __align__(16) float lL[4096];   // 16 KB: 128 rows x 32 k (crossed chunks)
    __shared__ __align__(16) short lBh[4096];  // 8 KB
    __shared__ __align__(16) short lBl[4096];  // 8 KB
    __shared__ float lM[512];
    __shared__ float lS[512];
    const int tid = threadIdx.x;
    const int w = tid >> 6, l = tid & 63;
    const int wm = w >> 1, wn = w & 1;
    const int bm = blockIdx.y * 128, bn = blockIdx.x * 128;
    const int l15 = l & 15, lq = l >> 4;
    const i64 koff = (i64)blockIdx.z * 512;

#pragma unroll
    for (int q = 0; q < 2; ++q) {
        lM[tid + q * 256] = colM[koff + tid + q * 256];
        lS[tid + q * 256] = colS[koff + tid + q * 256];
    }
    float o4[4];
#pragma unroll
    for (int i = 0; i < 4; ++i) o4[i] = o[bm + wm * 64 + i * 16 + l15];

    f32x4 acc[4][4] = {};
    for (int kt = 0; kt < 512; kt += 32) {
        __syncthreads();
#pragma unroll
        for (int rr = 0; rr < 4; ++rr) {
            const int r = w + rr * 4;          // region 0..15 (1 KB each)
            const int kb2 = r >> 1, mh = r & 1;
            ld16_lds(L + (i64)(bm + mh * 64 + l) * WH + koff + kt + kb2 * 4,
                     (char*)lL + r * 1024);
        }
#pragma unroll
        for (int rr = 0; rr < 2; ++rr) {
            const int r = w + rr * 4;          // region 0..7
            const int kb = r >> 1, mh = r & 1;
            const i64 bo = (i64)(bn + mh * 64 + l) * WH + koff + kt + kb * 8;
            ld16_lds(Bh + bo, (char*)lBh + r * 1024);
            ld16_lds(Bl + bo, (char*)lBl + r * 1024);
        }
        __syncthreads();
        float mv[8], sv[8];
        *(float4*)(mv)     = *(const float4*)(lM + kt + lq * 8);
        *(float4*)(mv + 4) = *(const float4*)(lM + kt + lq * 8 + 4);
        *(float4*)(sv)     = *(const float4*)(lS + kt + lq * 8);
        *(float4*)(sv + 4) = *(const float4*)(lS + kt + lq * 8 + 4);
        f16x8 bh[4], bl[4];
#pragma unroll
        for (int j = 0; j < 4; ++j) {
            const int ib = (lq * 128 + wn * 64 + j * 16 + l15) * 8;
            bh[j] = *(const f16x8*)(lBh + ib);
            bl[j] = *(const f16x8*)(lBl + ib);
        }
#pragma unroll
        for (int i = 0; i < 4; ++i) {
            const int mrow = wm * 64 + i * 16 + l15;
            const float* lp = lL + lq * 1024 + mrow * 4;
            float xv[8];
            *(float4*)(xv)     = *(const float4*)(lp);
            *(float4*)(xv + 4) = *(const float4*)(lp + 512);
            const float oi = o4[i];
            f16x8 ah, al;
#pragma unroll
            for (int e = 0; e < 8; ++e) {
                const float a = __expf(xv[e] - oi - mv[e]) * sv[e];
                const _Float16 hh = (_Float16)a;
                ah[e] = hh;
                al[e] = (_Float16)(a - (float)hh);
            }
#pragma unroll
            for (int j = 0; j < 4; ++j) {
                acc[i][j] = __builtin_amdgcn_mfma_f32_16x16x32_f16(ah, bh[j], acc[i][j], 0, 0, 0);
                acc[i][j] = __builtin_amdgcn_mfma_f32_16x16x32_f16(ah, bl[j], acc[i][j], 0, 0, 0);
                acc[i][j] = __builtin_amdgcn_mfma_f32_16x16x32_f16(al, bh[j], acc[i][j], 0, 0, 0);
            }
        }
    }
    float* P = Pw + (i64)blockIdx.z * ((i64)WH * CD);
#pragma unroll
    for (int i = 0; i < 4; ++i)
#pragma unroll
        for (int j = 0; j < 4; ++j) {
            const int n = bn + wn * 64 + j * 16 + l15;
            const int m0 = bm + wm * 64 + i * 16 + lq * 4;
#pragma unroll
            for (int r = 0; r < 4; ++r)
                P[(i64)(m0 + r) * CD + n] = acc[i][j][r];
        }
}

// -------- reduce 8 split-K partials into outf (which holds r)
__global__ __launch_bounds__(256) void k_red(const float* __restrict__ Pw,
                                             float* __restrict__ outp) {
    const i64 i = ((i64)blockIdx.x * 256 + threadIdx.x) * 4;
    float4 a = *(const float4*)(outp + i);
#pragma unroll
    for (int z = 0; z < 8; ++z) {
        const float4 p = *(const float4*)(Pw + (i64)z * ((i64)WH * CD) + i);
        a.x += p.x; a.y += p.y; a.z += p.z; a.w += p.w;
    }
    *(float4*)(outp + i) = a;
}

// -------- f32 -> (f16 hi, f16 lo) split
__global__ __launch_bounds__(256) void k_mksplit(const float* __restrict__ in,
                                                 unsigned short* __restrict__ hi,
                                                 unsigned short* __restrict__ lo, i64 n) {
    const i64 i = ((i64)blockIdx.x * 256 + threadIdx.x) * 4;
    if (i >= n) return;
    const float4 v = *(const float4*)(in + i);
    ushort4 h, l2;
    h.x = f2h(v.x); l2.x = f2h(v.x - h2f(h.x));
    h.y = f2h(v.y); l2.y = f2h(v.y - h2f(h.y));
    h.z = f2h(v.z); l2.z = f2h(v.z - h2f(h.z));
    h.w = f2h(v.w); l2.w = f2h(v.w - h2f(h.w));
    *(ushort4*)(hi + i) = h;
    *(ushort4*)(lo + i) = l2;
}

extern "C" void kernel_launch(void* const* d_in, const int* in_sizes, int n_in,
                              void* d_out, int out_size, void* d_ws, size_t ws_size,
                              hipStream_t stream) {
    (void)in_sizes; (void)n_in; (void)out_size; (void)ws_size;
    const float* skt = (const float*)d_in[0];
    const float* ref = (const float*)d_in[1];
    const float* Wa3 = (const float*)d_in[2];
    const float* ba3 = (const float*)d_in[3];
    const float* Wu3 = (const float*)d_in[4];
    const float* bu3 = (const float*)d_in[5];
    const float* Wa4 = (const float*)d_in[6];
    const float* ba4 = (const float*)d_in[7];
    const float* Wu4 = (const float*)d_in[8];
    const float* bu4 = (const float*)d_in[9];
    float* out = (float*)d_out;

    const i64 WHC = (i64)WH * CD;   // 1,048,576
    const i64 GM  = (i64)WH * WH;   // 16,777,216
    const i64 CC  = (i64)CD * CD;

    // workspace carve — total ~173 MB (proven-safe: 204.5 MB ran in rounds 4 & 7)
    auto al = [](size_t x) { return (x + 255) & ~(size_t)255; };
    char* p = (char*)d_ws; size_t off = 0;
    auto carve = [&](size_t bytes) { void* r = p + off; off += al(bytes); return r; };
    float* Lb             = (float*)carve((size_t)GM * 4);               // 67.1 MB
    unsigned short* skthi = (unsigned short*)carve((size_t)4 * WHC * 2);
    unsigned short* sktlo = (unsigned short*)carve((size_t)4 * WHC * 2);
    unsigned short* refhi = (unsigned short*)carve((size_t)4 * WHC * 2);
    unsigned short* reflo = (unsigned short*)carve((size_t)4 * WHC * 2);
    unsigned short* ghi   = (unsigned short*)carve((size_t)4 * WHC * 2);
    unsigned short* glo   = (unsigned short*)carve((size_t)4 * WHC * 2); // 6x8.39 MB
    unsigned short* axthi = (unsigned short*)carve((size_t)4 * WHC * 2);
    unsigned short* axtlo = (unsigned short*)carve((size_t)4 * WHC * 2); // 16.8 MB
    float* ob             = (float*)carve((size_t)WH * 4);
    float* colM           = (float*)carve((size_t)WH * 4);
    float* colS           = (float*)carve((size_t)WH * 4);
    float2* partb         = (float2*)carve((size_t)64 * WH * 8);         // 2.1 MB
    float2* rowPb         = (float2*)carve((size_t)32 * WH * 8);         // 1.05 MB
    unsigned short* Wthi  = (unsigned short*)carve((size_t)4 * CC * 2);
    unsigned short* Wtlo  = (unsigned short*)carve((size_t)4 * CC * 2);
    float* Pw             = (float*)carve((size_t)8 * WHC * 4);          // 33.6 MB

    dim3 thr(256), ttr(32, 8);
    k_trans<<<dim3(WH / 32, CD / 32, 4), ttr, 0, stream>>>(skt, skthi, sktlo, CD, WH, WHC, WHC);
    k_trans<<<dim3(WH / 32, CD / 32, 4), ttr, 0, stream>>>(ref, refhi, reflo, CD, WH, WHC, WHC);
    k_trans<<<dim3(CD / 32, CD / 32, 1), ttr, 0, stream>>>(Wa3, Wthi + 0 * CC, Wtlo + 0 * CC, CD, CD, 0, 0);
    k_trans<<<dim3(CD / 32, CD / 32, 1), ttr, 0, stream>>>(Wu3, Wthi + 1 * CC, Wtlo + 1 * CC, CD, CD, 0, 0);
    k_trans<<<dim3(CD / 32, CD / 32, 1), ttr, 0, stream>>>(Wa4, Wthi + 2 * CC, Wtlo + 2 * CC, CD, CD, 0, 0);
    k_trans<<<dim3(CD / 32, CD / 32, 1), ttr, 0, stream>>>(Wu4, Wthi + 3 * CC, Wtlo + 3 * CC, CD, CD, 0, 0);

    auto stage = [&](const unsigned short* shi, const unsigned short* slo,
                     const unsigned short* mhi, const unsigned short* mlo,
                     int widx, const float* ba, const float* bu, float* outf) {
        // ax = relu(msg @ Wa + ba), stored transposed as f16 split (all 4 batches)
        k_gemm<1><<<dim3(CD / 128, WH / 128, 4), thr, 0, stream>>>(
            mhi, mlo, CD, WHC, Wthi + (i64)widx * CC, Wtlo + (i64)widx * CC, CD, 0,
            nullptr, axthi, axtlo, WH, WHC, CD, ba, nullptr, nullptr, nullptr);
        // r = relu(src @ Wu + bu) + src  -> outf (all 4 batches)
        k_gemm<2><<<dim3(CD / 128, WH / 128, 4), thr, 0, stream>>>(
            shi, slo, CD, WHC, Wthi + (i64)(widx + 1) * CC, Wtlo + (i64)(widx + 1) * CC, CD, 0,
            outf, nullptr, nullptr, CD, WHC, CD, bu, shi, slo, nullptr);
        for (int b = 0; b < 4; ++b) {
            // logits -> Lb (f32) + fused row-stat partials
            k_gemm<0><<<dim3(WH / 128, WH / 128, 1), thr, 0, stream>>>(
                shi + (i64)b * WHC, slo + (i64)b * WHC, CD, 0,
                mhi + (i64)b * WHC, mlo + (i64)b * WHC, CD, 0,
                Lb, nullptr, nullptr, WH, 0, CD, nullptr, nullptr, nullptr, rowPb);
            k_finrow<<<dim3(WH / 256), thr, 0, stream>>>(rowPb, ob);
            k_colpart<<<dim3(WH / 256, WH / 64, 1), thr, 0, stream>>>(Lb, ob, partb);
            k_colreduce<<<dim3(WH / 256), thr, 0, stream>>>(partb, colM, colS);
            // P[z] = A(Lb)_chunk @ ax (split-K 8, plain stores)
            k_attn<<<dim3(CD / 128, WH / 128, 8), thr, 0, stream>>>(
                Lb, ob, colM, colS,
                axthi + (i64)b * WHC, axtlo + (i64)b * WHC, Pw);
            // outf[b] += sum_z P[z]
            k_red<<<dim3((unsigned)(WHC / 1024)), thr, 0, stream>>>(Pw, outf + (i64)b * WHC);
        }
    };

    // stage A: src = skt, msg = ref -> gen (accumulated in d_out)
    stage(skthi, sktlo, refhi, reflo, 0, ba3, bu3, out);
    k_mksplit<<<dim3((unsigned)(4 * WHC / 1024)), thr, 0, stream>>>(out, ghi, glo, 4 * WHC);
    // stage B: src = msg = gen -> final output (overwrites d_out)
    stage(ghi, glo, ghi, glo, 2, ba4, bu4, out);
}

// Round 9
// 1133.980 us; speedup vs baseline: 1.4434x; 1.0653x over previous
//
#include <hip/hip_runtime.h>
#include <cstdint>
#include <cstddef>

#define WH 4096
#define CD 256
typedef long long i64;

typedef __attribute__((ext_vector_type(8))) _Float16 f16x8;
typedef __attribute__((ext_vector_type(4))) float f32x4;

#define AS1 __attribute__((address_space(1)))
#define AS3 __attribute__((address_space(3)))

__device__ __forceinline__ unsigned short f2h(float f) {
    _Float16 h = (_Float16)f;
    return __builtin_bit_cast(unsigned short, h);
}
__device__ __forceinline__ float h2f(unsigned short u) {
    return (float)__builtin_bit_cast(_Float16, u);
}
__device__ __forceinline__ void ld16_lds(const void* g, void* l) {
    __builtin_amdgcn_global_load_lds((AS1 void*)g, (AS3 void*)l, 16, 0, 0);
}

// -------- transpose f32 (src-stride CC) -> f16 split (dst-stride RR)
__global__ __launch_bounds__(256) void k_trans(const float* __restrict__ src,
                                               unsigned short* __restrict__ dhi,
                                               unsigned short* __restrict__ dlo,
                                               int RR, int CC, i64 ss, i64 ds) {
    __shared__ float t[32][33];
    const float* s = src + (i64)blockIdx.z * ss;
    const int c0 = blockIdx.x * 32, r0 = blockIdx.y * 32;
    const int tx = threadIdx.x, ty = threadIdx.y;
#pragma unroll
    for (int i = 0; i < 4; ++i)
        t[ty + i * 8][tx] = s[(i64)(r0 + ty + i * 8) * CC + c0 + tx];
    __syncthreads();
#pragma unroll
    for (int i = 0; i < 4; ++i) {
        const i64 idx = (i64)blockIdx.z * ds + (i64)(c0 + ty + i * 8) * RR + r0 + tx;
        const float v = t[tx][ty + i * 8];
        const unsigned short hi = f2h(v);
        dhi[idx] = hi;
        dlo[idx] = f2h(v - h2f(hi));
    }
}

// -------- NT GEMM, split-f16: C = (Ah+Al)(Bh+Bl)^T via 3 MFMA products.
// MODE 0: f32 store (logits -> Lb) + fused per-block ROW stat partials (max,expsum over 128 cols)
// MODE 1: bias+relu, store transposed f16-split (ax -> axt hi/lo)
// MODE 2: bias+relu, add split residual, f32 store (r -> outf)
template <int MODE>
__global__ __launch_bounds__(256) void k_gemm(
    const unsigned short* __restrict__ A, const unsigned short* __restrict__ A2, int lda, i64 sA,
    const unsigned short* __restrict__ B, const unsigned short* __restrict__ B2, int ldb, i64 sB,
    float* __restrict__ Cf, unsigned short* __restrict__ Chi, unsigned short* __restrict__ Clo,
    int ldc, i64 sC, int K,
    const float* __restrict__ bias,
    const unsigned short* __restrict__ addh, const unsigned short* __restrict__ addl,
    float2* __restrict__ rowP) {
    __shared__ __align__(16) short lA[8192];
    __shared__ __align__(16) short lB[8192];
    __shared__ float2 redp[2][128];
    const int z = blockIdx.z;
    A += (i64)z * sA; A2 += (i64)z * sA;
    B += (i64)z * sB; B2 += (i64)z * sB;

    const int tid = threadIdx.x;
    const int w = tid >> 6, l = tid & 63;
    const int wm = w >> 1, wn = w & 1;
    const int bm = blockIdx.y * 128, bn = blockIdx.x * 128;
    const int l15 = l & 15, lq = l >> 4;

    f32x4 acc[4][4] = {};

    for (int kt = 0; kt < K; kt += 32) {
        __syncthreads();
#pragma unroll
        for (int rr = 0; rr < 2; ++rr) {
            const int r = w + rr * 4;          // region 0..7
            const int kb = r >> 1, mh = r & 1;
            const int row = mh * 64 + l;
            const i64 ao = (i64)(bm + row) * lda + kt + kb * 8;
            const i64 bo = (i64)(bn + row) * ldb + kt + kb * 8;
            ld16_lds(A + ao, (char*)lA + r * 1024);
            ld16_lds(B + bo, (char*)lB + r * 1024);
            ld16_lds(A2 + ao, (char*)lA + 8192 + r * 1024);
            ld16_lds(B2 + bo, (char*)lB + 8192 + r * 1024);
        }
        __syncthreads();
        f16x8 ah[4], bh[4], al[4], bl[4];
#pragma unroll
        for (int i = 0; i < 4; ++i) {
            const int ia = (lq * 128 + wm * 64 + i * 16 + l15) * 8;
            const int ib = (lq * 128 + wn * 64 + i * 16 + l15) * 8;
            ah[i] = *(const f16x8*)(lA + ia);
            bh[i] = *(const f16x8*)(lB + ib);
            al[i] = *(const f16x8*)(lA + 4096 + ia);
            bl[i] = *(const f16x8*)(lB + 4096 + ib);
        }
#pragma unroll
        for (int i = 0; i < 4; ++i)
#pragma unroll
            for (int j = 0; j < 4; ++j) {
                acc[i][j] = __builtin_amdgcn_mfma_f32_16x16x32_f16(ah[i], bh[j], acc[i][j], 0, 0, 0);
                acc[i][j] = __builtin_amdgcn_mfma_f32_16x16x32_f16(ah[i], bl[j], acc[i][j], 0, 0, 0);
                acc[i][j] = __builtin_amdgcn_mfma_f32_16x16x32_f16(al[i], bh[j], acc[i][j], 0, 0, 0);
            }
    }

#pragma unroll
    for (int i = 0; i < 4; ++i)
#pragma unroll
        for (int j = 0; j < 4; ++j) {
            const int n = bn + wn * 64 + j * 16 + l15;
            const int m0 = bm + wm * 64 + i * 16 + lq * 4;
            float bv = 0.f;
            if constexpr (MODE == 1 || MODE == 2) bv = bias[n];
            if constexpr (MODE == 1) {
                unsigned short hv[4], lv[4];
#pragma unroll
                for (int r = 0; r < 4; ++r) {
                    const float v = fmaxf(acc[i][j][r] + bv, 0.f);
                    hv[r] = f2h(v);
                    lv[r] = f2h(v - h2f(hv[r]));
                }
                const i64 tb = (i64)z * sC + (i64)n * ldc + m0;
                *(ushort4*)(Chi + tb) = make_ushort4(hv[0], hv[1], hv[2], hv[3]);
                *(ushort4*)(Clo + tb) = make_ushort4(lv[0], lv[1], lv[2], lv[3]);
            } else {
#pragma unroll
                for (int r = 0; r < 4; ++r) {
                    float v = acc[i][j][r];
                    const i64 idx = (i64)z * sC + (i64)(m0 + r) * ldc + n;
                    if constexpr (MODE == 0) {
                        Cf[idx] = v;
                    } else {  // MODE 2
                        v = fmaxf(v + bv, 0.f);
                        v += h2f(addh[idx]) + h2f(addl[idx]);
                        Cf[idx] = v;
                    }
                }
            }
        }

    if constexpr (MODE == 0) {
        // ---- fused row partials: (max, expsum) over this block's 128 cols, per row.
        float rm[16], rs[16];
#pragma unroll
        for (int i = 0; i < 4; ++i)
#pragma unroll
            for (int r = 0; r < 4; ++r) {
                float m = fmaxf(fmaxf(acc[i][0][r], acc[i][1][r]), fmaxf(acc[i][2][r], acc[i][3][r]));
                m = fmaxf(m, __shfl_xor(m, 1));
                m = fmaxf(m, __shfl_xor(m, 2));
                m = fmaxf(m, __shfl_xor(m, 4));
                m = fmaxf(m, __shfl_xor(m, 8));
                rm[i * 4 + r] = m;
                float s = __expf(acc[i][0][r] - m) + __expf(acc[i][1][r] - m)
                        + __expf(acc[i][2][r] - m) + __expf(acc[i][3][r] - m);
                s += __shfl_xor(s, 1); s += __shfl_xor(s, 2);
                s += __shfl_xor(s, 4); s += __shfl_xor(s, 8);
                rs[i * 4 + r] = s;
            }
        __syncthreads();
        if (l15 == 0) {
#pragma unroll
            for (int i = 0; i < 4; ++i)
#pragma unroll
                for (int r = 0; r < 4; ++r)
                    redp[wn][wm * 64 + i * 16 + lq * 4 + r] = make_float2(rm[i * 4 + r], rs[i * 4 + r]);
        }
        __syncthreads();
        if (tid < 128) {
            const float2 a = redp[0][tid], b = redp[1][tid];
            const float m = fmaxf(a.x, b.x);
            const float s = a.y * __expf(a.x - m) + b.y * __expf(b.x - m);
            rowP[(i64)blockIdx.x * WH + bm + tid] = make_float2(m, s);
        }
    }
}

// -------- fused: merge row partials -> o (own 64 rows, in LDS); col partials = plain exp-sum.
// grid (16, 64). Block x==0 publishes o for its row range.
__global__ __launch_bounds__(256) void k_colpart(const float* __restrict__ L,
                                                 const float2* __restrict__ rowP,
                                                 float* __restrict__ o,
                                                 float* __restrict__ part) {
    __shared__ float os[64];
    const int t = threadIdx.x;
    const int r0 = blockIdx.y * 64;
    if (t < 64) {
        float M = -3.4e38f, S = 0.f;
        for (int x = 0; x < 32; ++x) {
            const float2 p = rowP[(i64)x * WH + r0 + t];
            const float nm = fmaxf(M, p.x);
            S = S * __expf(M - nm) + p.y * __expf(p.x - nm);
            M = nm;
        }
        const float ov = M + __logf(S);
        os[t] = ov;
        if (blockIdx.x == 0) o[r0 + t] = ov;
    }
    __syncthreads();
    const int j = blockIdx.x * 256 + t;
    float ps = 0.f;
    for (int r = 0; r < 64; ++r)
        ps += __expf(L[(i64)(r0 + r) * WH + j] - os[r]);
    part[(i64)blockIdx.y * WH + j] = ps;
}

// -------- column reduce: C_j = sum of 64 partials; colS = 1/max(C, 1e-12)  (f32-native, matches ref)
__global__ __launch_bounds__(256) void k_colreduce(const float* __restrict__ part,
                                                   float* __restrict__ colS) {
    const int j = blockIdx.x * 256 + threadIdx.x;
    float C = 0.f;
    for (int rb = 0; rb < 64; ++rb) C += part[(i64)rb * WH + j];
    colS[j] = 1.f / fmaxf(C, 1e-12f);
}

// -------- fused attention: P[z] = [exp(L - o_i) * colS_j]_{k-chunk z} @ axt^T, f16 partial stores.
// grid (2, 32, 8): z = k-chunk of 512.
__global__ __launch_bounds__(256) void k_attn(
    const float* __restrict__ L, const float* __restrict__ o,
    const float* __restrict__ colS,
    const unsigned short* __restrict__ Bh, const unsigned short* __restrict__ Bl,
    unsigned short* __restrict__ Pw) {
    __shared__ __align__(16) float lL[4096];   // 16 KB: 128 rows x 32 k (crossed chunks)
    __shared__ __align__(16) short lBh[4096];  // 8 KB
    __shared__ __align__(16) short lBl[4096];  // 8 KB
    __shared__ float lS[512];
    const int tid = threadIdx.x;
    const int w = tid >> 6, l = tid & 63;
    const int wm = w >> 1, wn = w & 1;
    const int bm = blockIdx.y * 128, bn = blockIdx.x * 128;
    const int l15 = l & 15, lq = l >> 4;
    const i64 koff = (i64)blockIdx.z * 512;

#pragma unroll
    for (int q = 0; q < 2; ++q)
        lS[tid + q * 256] = colS[koff + tid + q * 256];
    float o4[4];
#pragma unroll
    for (int i = 0; i < 4; ++i) o4[i] = o[bm + wm * 64 + i * 16 + l15];

    f32x4 acc[4][4] = {};
    for (int kt = 0; kt < 512; kt += 32) {
        __syncthreads();
#pragma unroll
        for (int rr = 0; rr < 4; ++rr) {
            const int r = w + rr * 4;          // region 0..15 (1 KB each)
            const int kb2 = r >> 1, mh = r & 1;
            ld16_lds(L + (i64)(bm + mh * 64 + l) * WH + koff + kt + kb2 * 4,
                     (char*)lL + r * 1024);
        }
#pragma unroll
        for (int rr = 0; rr < 2; ++rr) {
            const int r = w + rr * 4;          // region 0..7
            const int kb = r >> 1, mh = r & 1;
            const i64 bo = (i64)(bn + mh * 64 + l) * WH + koff + kt + kb * 8;
            ld16_lds(Bh + bo, (char*)lBh + r * 1024);
            ld16_lds(Bl + bo, (char*)lBl + r * 1024);
        }
        __syncthreads();
        float sv[8];
        *(float4*)(sv)     = *(const float4*)(lS + kt + lq * 8);
        *(float4*)(sv + 4) = *(const float4*)(lS + kt + lq * 8 + 4);
        f16x8 bh[4], bl[4];
#pragma unroll
        for (int j = 0; j < 4; ++j) {
            const int ib = (lq * 128 + wn * 64 + j * 16 + l15) * 8;
            bh[j] = *(const f16x8*)(lBh + ib);
            bl[j] = *(const f16x8*)(lBl + ib);
        }
#pragma unroll
        for (int i = 0; i < 4; ++i) {
            const int mrow = wm * 64 + i * 16 + l15;
            const float* lp = lL + lq * 1024 + mrow * 4;
            float xv[8];
            *(float4*)(xv)     = *(const float4*)(lp);
            *(float4*)(xv + 4) = *(const float4*)(lp + 512);
            const float oi = o4[i];
            f16x8 ah, al;
#pragma unroll
            for (int e = 0; e < 8; ++e) {
                const float a = __expf(xv[e] - oi) * sv[e];
                const _Float16 hh = (_Float16)a;
                ah[e] = hh;
                al[e] = (_Float16)(a - (float)hh);
            }
#pragma unroll
            for (int j = 0; j < 4; ++j) {
                acc[i][j] = __builtin_amdgcn_mfma_f32_16x16x32_f16(ah, bh[j], acc[i][j], 0, 0, 0);
                acc[i][j] = __builtin_amdgcn_mfma_f32_16x16x32_f16(ah, bl[j], acc[i][j], 0, 0, 0);
                acc[i][j] = __builtin_amdgcn_mfma_f32_16x16x32_f16(al, bh[j], acc[i][j], 0, 0, 0);
            }
        }
    }
    unsigned short* P = Pw + (i64)blockIdx.z * ((i64)WH * CD);
#pragma unroll
    for (int i = 0; i < 4; ++i)
#pragma unroll
        for (int j = 0; j < 4; ++j) {
            const int n = bn + wn * 64 + j * 16 + l15;
            const int m0 = bm + wm * 64 + i * 16 + lq * 4;
#pragma unroll
            for (int r = 0; r < 4; ++r)
                P[(i64)(m0 + r) * CD + n] = f2h(acc[i][j][r]);
        }
}

// -------- reduce 8 f16 split-K partials into outf (holds r); optionally emit f16 split of result
template <int SPLIT>
__global__ __launch_bounds__(256) void k_red(const unsigned short* __restrict__ Pw,
                                             float* __restrict__ outp,
                                             unsigned short* __restrict__ hi,
                                             unsigned short* __restrict__ lo) {
    const i64 i = ((i64)blockIdx.x * 256 + threadIdx.x) * 4;
    float4 a = *(const float4*)(outp + i);
#pragma unroll
    for (int z = 0; z < 8; ++z) {
        const ushort4 p = *(const ushort4*)(Pw + (i64)z * ((i64)WH * CD) + i);
        a.x += h2f(p.x); a.y += h2f(p.y); a.z += h2f(p.z); a.w += h2f(p.w);
    }
    *(float4*)(outp + i) = a;
    if constexpr (SPLIT) {
        ushort4 h, l2;
        h.x = f2h(a.x); l2.x = f2h(a.x - h2f(h.x));
        h.y = f2h(a.y); l2.y = f2h(a.y - h2f(h.y));
        h.z = f2h(a.z); l2.z = f2h(a.z - h2f(h.z));
        h.w = f2h(a.w); l2.w = f2h(a.w - h2f(h.w));
        *(ushort4*)(hi + i) = h;
        *(ushort4*)(lo + i) = l2;
    }
}

extern "C" void kernel_launch(void* const* d_in, const int* in_sizes, int n_in,
                              void* d_out, int out_size, void* d_ws, size_t ws_size,
                              hipStream_t stream) {
    (void)in_sizes; (void)n_in; (void)out_size; (void)ws_size;
    const float* skt = (const float*)d_in[0];
    const float* ref = (const float*)d_in[1];
    const float* Wa3 = (const float*)d_in[2];
    const float* ba3 = (const float*)d_in[3];
    const float* Wu3 = (const float*)d_in[4];
    const float* bu3 = (const float*)d_in[5];
    const float* Wa4 = (const float*)d_in[6];
    const float* ba4 = (const float*)d_in[7];
    const float* Wu4 = (const float*)d_in[8];
    const float* bu4 = (const float*)d_in[9];
    float* out = (float*)d_out;

    const i64 WHC = (i64)WH * CD;   // 1,048,576
    const i64 GM  = (i64)WH * WH;   // 16,777,216
    const i64 CC  = (i64)CD * CD;

    // workspace carve — total ~152 MB (proven-safe: 204.5 MB ran in rounds 4/7/8)
    auto al = [](size_t x) { return (x + 255) & ~(size_t)255; };
    char* p = (char*)d_ws; size_t off = 0;
    auto carve = [&](size_t bytes) { void* r = p + off; off += al(bytes); return r; };
    float* Lb             = (float*)carve((size_t)GM * 4);               // 67.1 MB
    unsigned short* skthi = (unsigned short*)carve((size_t)4 * WHC * 2);
    unsigned short* sktlo = (unsigned short*)carve((size_t)4 * WHC * 2);
    unsigned short* refhi = (unsigned short*)carve((size_t)4 * WHC * 2);
    unsigned short* reflo = (unsigned short*)carve((size_t)4 * WHC * 2);
    unsigned short* ghi   = (unsigned short*)carve((size_t)4 * WHC * 2);
    unsigned short* glo   = (unsigned short*)carve((size_t)4 * WHC * 2); // 6x8.39 MB
    unsigned short* axthi = (unsigned short*)carve((size_t)4 * WHC * 2);
    unsigned short* axtlo = (unsigned short*)carve((size_t)4 * WHC * 2); // 16.8 MB
    float* ob             = (float*)carve((size_t)WH * 4);
    float* colS           = (float*)carve((size_t)WH * 4);
    float* partb          = (float*)carve((size_t)64 * WH * 4);          // 1.05 MB
    float2* rowPb         = (float2*)carve((size_t)32 * WH * 8);         // 1.05 MB
    unsigned short* Wthi  = (unsigned short*)carve((size_t)4 * CC * 2);
    unsigned short* Wtlo  = (unsigned short*)carve((size_t)4 * CC * 2);
    unsigned short* Pw    = (unsigned short*)carve((size_t)8 * WHC * 2); // 16.8 MB

    dim3 thr(256), ttr(32, 8);
    k_trans<<<dim3(WH / 32, CD / 32, 4), ttr, 0, stream>>>(skt, skthi, sktlo, CD, WH, WHC, WHC);
    k_trans<<<dim3(WH / 32, CD / 32, 4), ttr, 0, stream>>>(ref, refhi, reflo, CD, WH, WHC, WHC);
    k_trans<<<dim3(CD / 32, CD / 32, 1), ttr, 0, stream>>>(Wa3, Wthi + 0 * CC, Wtlo + 0 * CC, CD, CD, 0, 0);
    k_trans<<<dim3(CD / 32, CD / 32, 1), ttr, 0, stream>>>(Wu3, Wthi + 1 * CC, Wtlo + 1 * CC, CD, CD, 0, 0);
    k_trans<<<dim3(CD / 32, CD / 32, 1), ttr, 0, stream>>>(Wa4, Wthi + 2 * CC, Wtlo + 2 * CC, CD, CD, 0, 0);
    k_trans<<<dim3(CD / 32, CD / 32, 1), ttr, 0, stream>>>(Wu4, Wthi + 3 * CC, Wtlo + 3 * CC, CD, CD, 0, 0);

    auto stage = [&](const unsigned short* shi, const unsigned short* slo,
                     const unsigned short* mhi, const unsigned short* mlo,
                     int widx, const float* ba, const float* bu, float* outf,
                     unsigned short* ohi, unsigned short* olo) {
        // ax = relu(msg @ Wa + ba), stored transposed as f16 split (all 4 batches)
        k_gemm<1><<<dim3(CD / 128, WH / 128, 4), thr, 0, stream>>>(
            mhi, mlo, CD, WHC, Wthi + (i64)widx * CC, Wtlo + (i64)widx * CC, CD, 0,
            nullptr, axthi, axtlo, WH, WHC, CD, ba, nullptr, nullptr, nullptr);
        // r = relu(src @ Wu + bu) + src  -> outf (all 4 batches)
        k_gemm<2><<<dim3(CD / 128, WH / 128, 4), thr, 0, stream>>>(
            shi, slo, CD, WHC, Wthi + (i64)(widx + 1) * CC, Wtlo + (i64)(widx + 1) * CC, CD, 0,
            outf, nullptr, nullptr, CD, WHC, CD, bu, shi, slo, nullptr);
        for (int b = 0; b < 4; ++b) {
            // logits -> Lb (f32) + fused row-stat partials
            k_gemm<0><<<dim3(WH / 128, WH / 128, 1), thr, 0, stream>>>(
                shi + (i64)b * WHC, slo + (i64)b * WHC, CD, 0,
                mhi + (i64)b * WHC, mlo + (i64)b * WHC, CD, 0,
                Lb, nullptr, nullptr, WH, 0, CD, nullptr, nullptr, nullptr, rowPb);
            // fused o-finalize + col partials (plain f32 exp-sums)
            k_colpart<<<dim3(WH / 256, WH / 64, 1), thr, 0, stream>>>(Lb, rowPb, ob, partb);
            k_colreduce<<<dim3(WH / 256), thr, 0, stream>>>(partb, colS);
            // P[z] = A(Lb)_chunk @ ax (split-K 8, f16 partial stores)
            k_attn<<<dim3(CD / 128, WH / 128, 8), thr, 0, stream>>>(
                Lb, ob, colS, axthi + (i64)b * WHC, axtlo + (i64)b * WHC, Pw);
            // outf[b] += sum_z P[z]  (+ f16 split of gen for stage A)
            if (ohi)
                k_red<1><<<dim3((unsigned)(WHC / 1024)), thr, 0, stream>>>(
                    Pw, outf + (i64)b * WHC, ohi + (i64)b * WHC, olo + (i64)b * WHC);
            else
                k_red<0><<<dim3((unsigned)(WHC / 1024)), thr, 0, stream>>>(
                    Pw, outf + (i64)b * WHC, nullptr, nullptr);
        }
    };

    // stage A: src = skt, msg = ref -> gen (accumulated in d_out, split emitted to ghi/glo)
    stage(skthi, sktlo, refhi, reflo, 0, ba3, bu3, out, ghi, glo);
    // stage B: src = msg = gen -> final output (overwrites d_out)
    stage(ghi, glo, ghi, glo, 2, ba4, bu4, out, nullptr, nullptr);
}

// Round 10
// 1087.388 us; speedup vs baseline: 1.5052x; 1.0428x over previous
//
#include <hip/hip_runtime.h>
#include <cstdint>
#include <cstddef>

#define WH 4096
#define CD 256
typedef long long i64;

typedef __attribute__((ext_vector_type(8))) _Float16 f16x8;
typedef __attribute__((ext_vector_type(4))) float f32x4;

#define AS1 __attribute__((address_space(1)))
#define AS3 __attribute__((address_space(3)))

__device__ __forceinline__ unsigned short f2h(float f) {
    _Float16 h = (_Float16)f;
    return __builtin_bit_cast(unsigned short, h);
}
__device__ __forceinline__ float h2f(unsigned short u) {
    return (float)__builtin_bit_cast(_Float16, u);
}
__device__ __forceinline__ void ld16_lds(const void* g, void* l) {
    __builtin_amdgcn_global_load_lds((AS1 void*)g, (AS3 void*)l, 16, 0, 0);
}

// -------- transpose f32 (src-stride CC) -> f16 split (dst-stride RR)
__global__ __launch_bounds__(256) void k_trans(const float* __restrict__ src,
                                               unsigned short* __restrict__ dhi,
                                               unsigned short* __restrict__ dlo,
                                               int RR, int CC, i64 ss, i64 ds) {
    __shared__ float t[32][33];
    const float* s = src + (i64)blockIdx.z * ss;
    const int c0 = blockIdx.x * 32, r0 = blockIdx.y * 32;
    const int tx = threadIdx.x, ty = threadIdx.y;
#pragma unroll
    for (int i = 0; i < 4; ++i)
        t[ty + i * 8][tx] = s[(i64)(r0 + ty + i * 8) * CC + c0 + tx];
    __syncthreads();
#pragma unroll
    for (int i = 0; i < 4; ++i) {
        const i64 idx = (i64)blockIdx.z * ds + (i64)(c0 + ty + i * 8) * RR + r0 + tx;
        const float v = t[tx][ty + i * 8];
        const unsigned short hi = f2h(v);
        dhi[idx] = hi;
        dlo[idx] = f2h(v - h2f(hi));
    }
}

// -------- NT GEMM, f16. SPLIT3=1: (Ah+Al)(Bh+Bl)^T via 3 MFMA products; SPLIT3=0: Ah*Bh^T only.
// MODE 0: f32 store (logits -> Lb) + fused per-block ROW stat partials (max,expsum over 128 cols)
// MODE 1: bias+relu, store transposed f16-split (ax -> axt hi/lo)
// MODE 2: bias+relu, add split residual, f32 store (r -> outf)
template <int MODE, int SPLIT3>
__global__ __launch_bounds__(256) void k_gemm(
    const unsigned short* __restrict__ A, const unsigned short* __restrict__ A2, int lda, i64 sA,
    const unsigned short* __restrict__ B, const unsigned short* __restrict__ B2, int ldb, i64 sB,
    float* __restrict__ Cf, unsigned short* __restrict__ Chi, unsigned short* __restrict__ Clo,
    int ldc, i64 sC, int K,
    const float* __restrict__ bias,
    const unsigned short* __restrict__ addh, const unsigned short* __restrict__ addl,
    float2* __restrict__ rowP) {
    __shared__ __align__(16) short lA[SPLIT3 ? 8192 : 4096];
    __shared__ __align__(16) short lB[SPLIT3 ? 8192 : 4096];
    __shared__ float2 redp[2][128];
    const int z = blockIdx.z;
    A += (i64)z * sA; B += (i64)z * sB;
    if constexpr (SPLIT3) { A2 += (i64)z * sA; B2 += (i64)z * sB; }

    const int tid = threadIdx.x;
    const int w = tid >> 6, l = tid & 63;
    const int wm = w >> 1, wn = w & 1;
    const int bm = blockIdx.y * 128, bn = blockIdx.x * 128;
    const int l15 = l & 15, lq = l >> 4;

    f32x4 acc[4][4] = {};

    for (int kt = 0; kt < K; kt += 32) {
        __syncthreads();
#pragma unroll
        for (int rr = 0; rr < 2; ++rr) {
            const int r = w + rr * 4;          // region 0..7
            const int kb = r >> 1, mh = r & 1;
            const int row = mh * 64 + l;
            const i64 ao = (i64)(bm + row) * lda + kt + kb * 8;
            const i64 bo = (i64)(bn + row) * ldb + kt + kb * 8;
            ld16_lds(A + ao, (char*)lA + r * 1024);
            ld16_lds(B + bo, (char*)lB + r * 1024);
            if constexpr (SPLIT3) {
                ld16_lds(A2 + ao, (char*)lA + 8192 + r * 1024);
                ld16_lds(B2 + bo, (char*)lB + 8192 + r * 1024);
            }
        }
        __syncthreads();
        f16x8 ah[4], bh[4], al[4], bl[4];
#pragma unroll
        for (int i = 0; i < 4; ++i) {
            const int ia = (lq * 128 + wm * 64 + i * 16 + l15) * 8;
            const int ib = (lq * 128 + wn * 64 + i * 16 + l15) * 8;
            ah[i] = *(const f16x8*)(lA + ia);
            bh[i] = *(const f16x8*)(lB + ib);
            if constexpr (SPLIT3) {
                al[i] = *(const f16x8*)(lA + 4096 + ia);
                bl[i] = *(const f16x8*)(lB + 4096 + ib);
            }
        }
#pragma unroll
        for (int i = 0; i < 4; ++i)
#pragma unroll
            for (int j = 0; j < 4; ++j) {
                acc[i][j] = __builtin_amdgcn_mfma_f32_16x16x32_f16(ah[i], bh[j], acc[i][j], 0, 0, 0);
                if constexpr (SPLIT3) {
                    acc[i][j] = __builtin_amdgcn_mfma_f32_16x16x32_f16(ah[i], bl[j], acc[i][j], 0, 0, 0);
                    acc[i][j] = __builtin_amdgcn_mfma_f32_16x16x32_f16(al[i], bh[j], acc[i][j], 0, 0, 0);
                }
            }
    }

#pragma unroll
    for (int i = 0; i < 4; ++i)
#pragma unroll
        for (int j = 0; j < 4; ++j) {
            const int n = bn + wn * 64 + j * 16 + l15;
            const int m0 = bm + wm * 64 + i * 16 + lq * 4;
            float bv = 0.f;
            if constexpr (MODE == 1 || MODE == 2) bv = bias[n];
            if constexpr (MODE == 1) {
                unsigned short hv[4], lv[4];
#pragma unroll
                for (int r = 0; r < 4; ++r) {
                    const float v = fmaxf(acc[i][j][r] + bv, 0.f);
                    hv[r] = f2h(v);
                    lv[r] = f2h(v - h2f(hv[r]));
                }
                const i64 tb = (i64)z * sC + (i64)n * ldc + m0;
                *(ushort4*)(Chi + tb) = make_ushort4(hv[0], hv[1], hv[2], hv[3]);
                *(ushort4*)(Clo + tb) = make_ushort4(lv[0], lv[1], lv[2], lv[3]);
            } else {
#pragma unroll
                for (int r = 0; r < 4; ++r) {
                    float v = acc[i][j][r];
                    const i64 idx = (i64)z * sC + (i64)(m0 + r) * ldc + n;
                    if constexpr (MODE == 0) {
                        Cf[idx] = v;
                    } else {  // MODE 2
                        v = fmaxf(v + bv, 0.f);
                        v += h2f(addh[idx]) + h2f(addl[idx]);
                        Cf[idx] = v;
                    }
                }
            }
        }

    if constexpr (MODE == 0) {
        // ---- fused row partials: (max, expsum) over this block's 128 cols, per row.
        float rm[16], rs[16];
#pragma unroll
        for (int i = 0; i < 4; ++i)
#pragma unroll
            for (int r = 0; r < 4; ++r) {
                float m = fmaxf(fmaxf(acc[i][0][r], acc[i][1][r]), fmaxf(acc[i][2][r], acc[i][3][r]));
                m = fmaxf(m, __shfl_xor(m, 1));
                m = fmaxf(m, __shfl_xor(m, 2));
                m = fmaxf(m, __shfl_xor(m, 4));
                m = fmaxf(m, __shfl_xor(m, 8));
                rm[i * 4 + r] = m;
                float s = __expf(acc[i][0][r] - m) + __expf(acc[i][1][r] - m)
                        + __expf(acc[i][2][r] - m) + __expf(acc[i][3][r] - m);
                s += __shfl_xor(s, 1); s += __shfl_xor(s, 2);
                s += __shfl_xor(s, 4); s += __shfl_xor(s, 8);
                rs[i * 4 + r] = s;
            }
        __syncthreads();
        if (l15 == 0) {
#pragma unroll
            for (int i = 0; i < 4; ++i)
#pragma unroll
                for (int r = 0; r < 4; ++r)
                    redp[wn][wm * 64 + i * 16 + lq * 4 + r] = make_float2(rm[i * 4 + r], rs[i * 4 + r]);
        }
        __syncthreads();
        if (tid < 128) {
            const float2 a = redp[0][tid], b = redp[1][tid];
            const float m = fmaxf(a.x, b.x);
            const float s = a.y * __expf(a.x - m) + b.y * __expf(b.x - m);
            rowP[(i64)blockIdx.x * WH + bm + tid] = make_float2(m, s);
        }
    }
}

// -------- fused: merge row partials -> o (own 64 rows, in LDS); col partials = plain exp-sum.
// grid (16, 64). Block x==0 publishes o for its row range.
__global__ __launch_bounds__(256) void k_colpart(const float* __restrict__ L,
                                                 const float2* __restrict__ rowP,
                                                 float* __restrict__ o,
                                                 float* __restrict__ part) {
    __shared__ float os[64];
    const int t = threadIdx.x;
    const int r0 = blockIdx.y * 64;
    if (t < 64) {
        float M = -3.4e38f, S = 0.f;
        for (int x = 0; x < 32; ++x) {
            const float2 p = rowP[(i64)x * WH + r0 + t];
            const float nm = fmaxf(M, p.x);
            S = S * __expf(M - nm) + p.y * __expf(p.x - nm);
            M = nm;
        }
        const float ov = M + __logf(S);
        os[t] = ov;
        if (blockIdx.x == 0) o[r0 + t] = ov;
    }
    __syncthreads();
    const int j = blockIdx.x * 256 + t;
    float ps = 0.f;
    for (int r = 0; r < 64; ++r)
        ps += __expf(L[(i64)(r0 + r) * WH + j] - os[r]);
    part[(i64)blockIdx.y * WH + j] = ps;
}

// -------- column reduce: C_j = sum of 64 partials; colS = 1/max(C, 1e-12)  (f32-native, matches ref)
__global__ __launch_bounds__(256) void k_colreduce(const float* __restrict__ part,
                                                   float* __restrict__ colS) {
    const int j = blockIdx.x * 256 + threadIdx.x;
    float C = 0.f;
    for (int rb = 0; rb < 64; ++rb) C += part[(i64)rb * WH + j];
    colS[j] = 1.f / fmaxf(C, 1e-12f);
}

// -------- fused attention: P[z] = [exp(L - o_i) * colS_j]_{k-chunk z} @ axt^T, f16 partial stores.
// FULL=1: split A and B (3 MFMA); FULL=0: hi-only (1 MFMA, post-softmax stage-B precision).
// grid (2, 32, 8): z = k-chunk of 512.
template <int FULL>
__global__ __launch_bounds__(256) void k_attn(
    const float* __restrict__ L, const float* __restrict__ o,
    const float* __restrict__ colS,
    const unsigned short* __restrict__ Bh, const unsigned short* __restrict__ Bl,
    unsigned short* __restrict__ Pw) {
    __shared__ __align__(16) float lL[4096];   // 16 KB: 128 rows x 32 k (crossed chunks)
    __shared__ __align__(16) short lBh[4096];  // 8 KB
    __shared__ __align__(16) short lBl[FULL ? 4096 : 64];
    __shared__ float lS[512];
    const int tid = threadIdx.x;
    const int w = tid >> 6, l = tid & 63;
    const int wm = w >> 1, wn = w & 1;
    const int bm = blockIdx.y * 128, bn = blockIdx.x * 128;
    const int l15 = l & 15, lq = l >> 4;
    const i64 koff = (i64)blockIdx.z * 512;

#pragma unroll
    for (int q = 0; q < 2; ++q)
        lS[tid + q * 256] = colS[koff + tid + q * 256];
    float o4[4];
#pragma unroll
    for (int i = 0; i < 4; ++i) o4[i] = o[bm + wm * 64 + i * 16 + l15];

    f32x4 acc[4][4] = {};
    for (int kt = 0; kt < 512; kt += 32) {
        __syncthreads();
#pragma unroll
        for (int rr = 0; rr < 4; ++rr) {
            const int r = w + rr * 4;          // region 0..15 (1 KB each)
            const int kb2 = r >> 1, mh = r & 1;
            ld16_lds(L + (i64)(bm + mh * 64 + l) * WH + koff + kt + kb2 * 4,
                     (char*)lL + r * 1024);
        }
#pragma unroll
        for (int rr = 0; rr < 2; ++rr) {
            const int r = w + rr * 4;          // region 0..7
            const int kb = r >> 1, mh = r & 1;
            const i64 bo = (i64)(bn + mh * 64 + l) * WH + koff + kt + kb * 8;
            ld16_lds(Bh + bo, (char*)lBh + r * 1024);
            if constexpr (FULL) ld16_lds(Bl + bo, (char*)lBl + r * 1024);
        }
        __syncthreads();
        float sv[8];
        *(float4*)(sv)     = *(const float4*)(lS + kt + lq * 8);
        *(float4*)(sv + 4) = *(const float4*)(lS + kt + lq * 8 + 4);
        f16x8 bh[4], bl[4];
#pragma unroll
        for (int j = 0; j < 4; ++j) {
            const int ib = (lq * 128 + wn * 64 + j * 16 + l15) * 8;
            bh[j] = *(const f16x8*)(lBh + ib);
            if constexpr (FULL) bl[j] = *(const f16x8*)(lBl + ib);
        }
#pragma unroll
        for (int i = 0; i < 4; ++i) {
            const int mrow = wm * 64 + i * 16 + l15;
            const float* lp = lL + lq * 1024 + mrow * 4;
            float xv[8];
            *(float4*)(xv)     = *(const float4*)(lp);
            *(float4*)(xv + 4) = *(const float4*)(lp + 512);
            const float oi = o4[i];
            f16x8 ah, al;
#pragma unroll
            for (int e = 0; e < 8; ++e) {
                const float a = __expf(xv[e] - oi) * sv[e];
                const _Float16 hh = (_Float16)a;
                ah[e] = hh;
                if constexpr (FULL) al[e] = (_Float16)(a - (float)hh);
            }
#pragma unroll
            for (int j = 0; j < 4; ++j) {
                acc[i][j] = __builtin_amdgcn_mfma_f32_16x16x32_f16(ah, bh[j], acc[i][j], 0, 0, 0);
                if constexpr (FULL) {
                    acc[i][j] = __builtin_amdgcn_mfma_f32_16x16x32_f16(ah, bl[j], acc[i][j], 0, 0, 0);
                    acc[i][j] = __builtin_amdgcn_mfma_f32_16x16x32_f16(al, bh[j], acc[i][j], 0, 0, 0);
                }
            }
        }
    }
    unsigned short* P = Pw + (i64)blockIdx.z * ((i64)WH * CD);
#pragma unroll
    for (int i = 0; i < 4; ++i)
#pragma unroll
        for (int j = 0; j < 4; ++j) {
            const int n = bn + wn * 64 + j * 16 + l15;
            const int m0 = bm + wm * 64 + i * 16 + lq * 4;
#pragma unroll
            for (int r = 0; r < 4; ++r)
                P[(i64)(m0 + r) * CD + n] = f2h(acc[i][j][r]);
        }
}

// -------- reduce 8 f16 split-K partials into outf (holds r); optionally emit f16 split of result
template <int SPLIT>
__global__ __launch_bounds__(256) void k_red(const unsigned short* __restrict__ Pw,
                                             float* __restrict__ outp,
                                             unsigned short* __restrict__ hi,
                                             unsigned short* __restrict__ lo) {
    const i64 i = ((i64)blockIdx.x * 256 + threadIdx.x) * 4;
    float4 a = *(const float4*)(outp + i);
#pragma unroll
    for (int z = 0; z < 8; ++z) {
        const ushort4 p = *(const ushort4*)(Pw + (i64)z * ((i64)WH * CD) + i);
        a.x += h2f(p.x); a.y += h2f(p.y); a.z += h2f(p.z); a.w += h2f(p.w);
    }
    *(float4*)(outp + i) = a;
    if constexpr (SPLIT) {
        ushort4 h, l2;
        h.x = f2h(a.x); l2.x = f2h(a.x - h2f(h.x));
        h.y = f2h(a.y); l2.y = f2h(a.y - h2f(h.y));
        h.z = f2h(a.z); l2.z = f2h(a.z - h2f(h.z));
        h.w = f2h(a.w); l2.w = f2h(a.w - h2f(h.w));
        *(ushort4*)(hi + i) = h;
        *(ushort4*)(lo + i) = l2;
    }
}

extern "C" void kernel_launch(void* const* d_in, const int* in_sizes, int n_in,
                              void* d_out, int out_size, void* d_ws, size_t ws_size,
                              hipStream_t stream) {
    (void)in_sizes; (void)n_in; (void)out_size; (void)ws_size;
    const float* skt = (const float*)d_in[0];
    const float* ref = (const float*)d_in[1];
    const float* Wa3 = (const float*)d_in[2];
    const float* ba3 = (const float*)d_in[3];
    const float* Wu3 = (const float*)d_in[4];
    const float* bu3 = (const float*)d_in[5];
    const float* Wa4 = (const float*)d_in[6];
    const float* ba4 = (const float*)d_in[7];
    const float* Wu4 = (const float*)d_in[8];
    const float* bu4 = (const float*)d_in[9];
    float* out = (float*)d_out;

    const i64 WHC = (i64)WH * CD;   // 1,048,576
    const i64 GM  = (i64)WH * WH;   // 16,777,216
    const i64 CC  = (i64)CD * CD;

    // workspace carve — total ~152 MB (proven-safe: 204.5 MB ran in rounds 4/7/8)
    auto al = [](size_t x) { return (x + 255) & ~(size_t)255; };
    char* p = (char*)d_ws; size_t off = 0;
    auto carve = [&](size_t bytes) { void* r = p + off; off += al(bytes); return r; };
    float* Lb             = (float*)carve((size_t)GM * 4);               // 67.1 MB
    unsigned short* skthi = (unsigned short*)carve((size_t)4 * WHC * 2);
    unsigned short* sktlo = (unsigned short*)carve((size_t)4 * WHC * 2);
    unsigned short* refhi = (unsigned short*)carve((size_t)4 * WHC * 2);
    unsigned short* reflo = (unsigned short*)carve((size_t)4 * WHC * 2);
    unsigned short* ghi   = (unsigned short*)carve((size_t)4 * WHC * 2);
    unsigned short* glo   = (unsigned short*)carve((size_t)4 * WHC * 2); // 6x8.39 MB
    unsigned short* axthi = (unsigned short*)carve((size_t)4 * WHC * 2);
    unsigned short* axtlo = (unsigned short*)carve((size_t)4 * WHC * 2); // 16.8 MB
    float* ob             = (float*)carve((size_t)WH * 4);
    float* colS           = (float*)carve((size_t)WH * 4);
    float* partb          = (float*)carve((size_t)64 * WH * 4);          // 1.05 MB
    float2* rowPb         = (float2*)carve((size_t)32 * WH * 8);         // 1.05 MB
    unsigned short* Wthi  = (unsigned short*)carve((size_t)4 * CC * 2);
    unsigned short* Wtlo  = (unsigned short*)carve((size_t)4 * CC * 2);
    unsigned short* Pw    = (unsigned short*)carve((size_t)8 * WHC * 2); // 16.8 MB

    dim3 thr(256), ttr(32, 8);
    k_trans<<<dim3(WH / 32, CD / 32, 4), ttr, 0, stream>>>(skt, skthi, sktlo, CD, WH, WHC, WHC);
    k_trans<<<dim3(WH / 32, CD / 32, 4), ttr, 0, stream>>>(ref, refhi, reflo, CD, WH, WHC, WHC);
    k_trans<<<dim3(CD / 32, CD / 32, 1), ttr, 0, stream>>>(Wa3, Wthi + 0 * CC, Wtlo + 0 * CC, CD, CD, 0, 0);
    k_trans<<<dim3(CD / 32, CD / 32, 1), ttr, 0, stream>>>(Wu3, Wthi + 1 * CC, Wtlo + 1 * CC, CD, CD, 0, 0);
    k_trans<<<dim3(CD / 32, CD / 32, 1), ttr, 0, stream>>>(Wa4, Wthi + 2 * CC, Wtlo + 2 * CC, CD, CD, 0, 0);
    k_trans<<<dim3(CD / 32, CD / 32, 1), ttr, 0, stream>>>(Wu4, Wthi + 3 * CC, Wtlo + 3 * CC, CD, CD, 0, 0);

    // FULL3 = 1: stage A (feeds stage-B softmax, needs split precision); 0: stage B (output-linear)
    auto stage = [&](const unsigned short* shi, const unsigned short* slo,
                     const unsigned short* mhi, const unsigned short* mlo,
                     int widx, const float* ba, const float* bu, float* outf,
                     unsigned short* ohi, unsigned short* olo, int FULL3) {
        // ax = relu(msg @ Wa + ba), stored transposed as f16 split (all 4 batches)
        if (FULL3)
            k_gemm<1, 1><<<dim3(CD / 128, WH / 128, 4), thr, 0, stream>>>(
                mhi, mlo, CD, WHC, Wthi + (i64)widx * CC, Wtlo + (i64)widx * CC, CD, 0,
                nullptr, axthi, axtlo, WH, WHC, CD, ba, nullptr, nullptr, nullptr);
        else
            k_gemm<1, 0><<<dim3(CD / 128, WH / 128, 4), thr, 0, stream>>>(
                mhi, nullptr, CD, WHC, Wthi + (i64)widx * CC, nullptr, CD, 0,
                nullptr, axthi, axtlo, WH, WHC, CD, ba, nullptr, nullptr, nullptr);
        // r = relu(src @ Wu + bu) + src  -> outf (all 4 batches)
        if (FULL3)
            k_gemm<2, 1><<<dim3(CD / 128, WH / 128, 4), thr, 0, stream>>>(
                shi, slo, CD, WHC, Wthi + (i64)(widx + 1) * CC, Wtlo + (i64)(widx + 1) * CC, CD, 0,
                outf, nullptr, nullptr, CD, WHC, CD, bu, shi, slo, nullptr);
        else
            k_gemm<2, 0><<<dim3(CD / 128, WH / 128, 4), thr, 0, stream>>>(
                shi, nullptr, CD, WHC, Wthi + (i64)(widx + 1) * CC, nullptr, CD, 0,
                outf, nullptr, nullptr, CD, WHC, CD, bu, shi, slo, nullptr);
        for (int b = 0; b < 4; ++b) {
            // logits -> Lb (f32) + fused row-stat partials — ALWAYS split (pre-softmax)
            k_gemm<0, 1><<<dim3(WH / 128, WH / 128, 1), thr, 0, stream>>>(
                shi + (i64)b * WHC, slo + (i64)b * WHC, CD, 0,
                mhi + (i64)b * WHC, mlo + (i64)b * WHC, CD, 0,
                Lb, nullptr, nullptr, WH, 0, CD, nullptr, nullptr, nullptr, rowPb);
            // fused o-finalize + col partials (plain f32 exp-sums)
            k_colpart<<<dim3(WH / 256, WH / 64, 1), thr, 0, stream>>>(Lb, rowPb, ob, partb);
            k_colreduce<<<dim3(WH / 256), thr, 0, stream>>>(partb, colS);
            // P[z] = A(Lb)_chunk @ ax (split-K 8, f16 partial stores)
            if (FULL3)
                k_attn<1><<<dim3(CD / 128, WH / 128, 8), thr, 0, stream>>>(
                    Lb, ob, colS, axthi + (i64)b * WHC, axtlo + (i64)b * WHC, Pw);
            else
                k_attn<0><<<dim3(CD / 128, WH / 128, 8), thr, 0, stream>>>(
                    Lb, ob, colS, axthi + (i64)b * WHC, nullptr, Pw);
            // outf[b] += sum_z P[z]  (+ f16 split of gen for stage A)
            if (ohi)
                k_red<1><<<dim3((unsigned)(WHC / 1024)), thr, 0, stream>>>(
                    Pw, outf + (i64)b * WHC, ohi + (i64)b * WHC, olo + (i64)b * WHC);
            else
                k_red<0><<<dim3((unsigned)(WHC / 1024)), thr, 0, stream>>>(
                    Pw, outf + (i64)b * WHC, nullptr, nullptr);
        }
    };

    // stage A: src = skt, msg = ref -> gen (accumulated in d_out, split emitted to ghi/glo)
    stage(skthi, sktlo, refhi, reflo, 0, ba3, bu3, out, ghi, glo, 1);
    // stage B: src = msg = gen -> final output (overwrites d_out); post-softmax paths hi-only
    stage(ghi, glo, ghi, glo, 2, ba4, bu4, out, nullptr, nullptr, 0);
}